// Round 5
// baseline (1321.084 us; speedup 1.0000x reference)
//
#include <hip/hip_runtime.h>
#include <math.h>

#define NN 10000
#define EE 160000
#define CH 16

#define RS128 0.08838834764831845f   // 1/sqrt(128)
#define RS384 0.05103103630798287f   // 1/sqrt(384)
#define RS32  0.17677669529663687f   // 1/sqrt(32)
#define R3    0.57735026918962576f   // 1/sqrt(3)
#define C1V   0.86602540378443865f   // sqrt(3)/2

__device__ __forceinline__ float sspf(float x) {
    return fmaxf(x, 0.0f) + log1pf(__expf(-fabsf(x))) - 0.69314718055994530942f;
}

// out = irrep_linear(X, W0, b0, W1). In-place safe per block (stages tile first).
__global__ __launch_bounds__(256) void k_irrep(
    const float* __restrict__ X, const float* __restrict__ W0,
    const float* __restrict__ b0, const float* __restrict__ W1,
    float* __restrict__ out) {
    __shared__ float xs_t[16][128];
    __shared__ float xv_t[16][384];
    const int t = threadIdx.x;
    const int nb = blockIdx.x * 16;
    for (int idx = t; idx < 16 * 512; idx += 256) {
        int n = idx >> 9, c = idx & 511;
        float v = X[(size_t)(nb + n) * 512 + c];
        if (c < 128) xs_t[n][c] = v; else xv_t[n][c - 128] = v;
    }
    __syncthreads();
    const int col = t & 127, half = t >> 7;
    float accs[8] = {0, 0, 0, 0, 0, 0, 0, 0};
    float accv[24] = {0};
    for (int u = 0; u < 128; ++u) {
        float w0 = W0[u * 128 + col];
        float w1 = W1[u * 128 + col];
#pragma unroll
        for (int i = 0; i < 8; ++i) {
            int n = half * 8 + i;
            accs[i] = fmaf(xs_t[n][u], w0, accs[i]);
            accv[3 * i + 0] = fmaf(xv_t[n][3 * u + 0], w1, accv[3 * i + 0]);
            accv[3 * i + 1] = fmaf(xv_t[n][3 * u + 1], w1, accv[3 * i + 1]);
            accv[3 * i + 2] = fmaf(xv_t[n][3 * u + 2], w1, accv[3 * i + 2]);
        }
    }
    float bias = b0[col];
#pragma unroll
    for (int i = 0; i < 8; ++i) {
        size_t gn = (size_t)(nb + half * 8 + i) * 512;
        out[gn + col] = accs[i] * RS128 + bias;
        out[gn + 128 + 3 * col + 0] = accv[3 * i + 0] * RS128;
        out[gn + 128 + 3 * col + 1] = accv[3 * i + 1] * RS128;
        out[gn + 128 + 3 * col + 2] = accv[3 * i + 2] * RS128;
    }
}

// self_x = irrep_linear(norm_gate(x), Wn0, bn0, Wn1)
__global__ __launch_bounds__(256) void k_self(
    const float* __restrict__ X,
    const float* __restrict__ ngW1, const float* __restrict__ ngb1,
    const float* __restrict__ ngW2, const float* __restrict__ ngb2,
    const float* __restrict__ Wn0, const float* __restrict__ bn0,
    const float* __restrict__ Wn1,
    float* __restrict__ selfx) {
    __shared__ float xv_t[16][384];
    __shared__ float f0_t[16][256];
    __shared__ float t1_t[16][256];
    const int t = threadIdx.x;
    const int nb = blockIdx.x * 16;
    for (int idx = t; idx < 16 * 512; idx += 256) {
        int n = idx >> 9, c = idx & 511;
        float v = X[(size_t)(nb + n) * 512 + c];
        if (c < 128) f0_t[n][c] = v; else xv_t[n][c - 128] = v;
    }
    __syncthreads();
    for (int idx = t; idx < 16 * 128; idx += 256) {
        int n = idx >> 7, u = idx & 127;
        float a = xv_t[n][3 * u], b = xv_t[n][3 * u + 1], c = xv_t[n][3 * u + 2];
        f0_t[n][128 + u] = sqrtf(fmaf(a, a, fmaf(b, b, fmaf(c, c, 1e-12f))));
    }
    __syncthreads();
    {
        float acc[16] = {0};
        for (int k = 0; k < 256; ++k) {
            float w = ngW1[k * 256 + t];
#pragma unroll
            for (int n = 0; n < 16; ++n) acc[n] = fmaf(f0_t[n][k], w, acc[n]);
        }
        float b1 = ngb1[t];
#pragma unroll
        for (int n = 0; n < 16; ++n) {
            float z = acc[n] + b1;
            t1_t[n][t] = z * (1.0f / (1.0f + __expf(-z)));
        }
    }
    __syncthreads();
    {
        float acc[16] = {0};
        for (int k = 0; k < 256; ++k) {
            float w = ngW2[k * 256 + t];
#pragma unroll
            for (int n = 0; n < 16; ++n) acc[n] = fmaf(t1_t[n][k], w, acc[n]);
        }
        float b2 = ngb2[t];
#pragma unroll
        for (int n = 0; n < 16; ++n) f0_t[n][t] = acc[n] + b2;
    }
    __syncthreads();
    for (int idx = t; idx < 16 * 384; idx += 256) {
        int n = idx / 384, j = idx % 384;
        xv_t[n][j] *= f0_t[n][128 + j / 3];
    }
    __syncthreads();
    const int col = t & 127, half = t >> 7;
    float accs[8] = {0, 0, 0, 0, 0, 0, 0, 0};
    float accv[24] = {0};
    for (int u = 0; u < 128; ++u) {
        float w0 = Wn0[u * 128 + col];
        float w1 = Wn1[u * 128 + col];
#pragma unroll
        for (int i = 0; i < 8; ++i) {
            int n = half * 8 + i;
            accs[i] = fmaf(f0_t[n][u], w0, accs[i]);
            accv[3 * i + 0] = fmaf(xv_t[n][3 * u + 0], w1, accv[3 * i + 0]);
            accv[3 * i + 1] = fmaf(xv_t[n][3 * u + 1], w1, accv[3 * i + 1]);
            accv[3 * i + 2] = fmaf(xv_t[n][3 * u + 2], w1, accv[3 * i + 2]);
        }
    }
    float bias = bn0[col];
#pragma unroll
    for (int i = 0; i < 8; ++i) {
        size_t gn = (size_t)(nb + half * 8 + i) * 512;
        selfx[gn + col] = accs[i] * RS128 + bias;
        selfx[gn + 128 + 3 * col + 0] = accv[3 * i + 0] * RS128;
        selfx[gn + 128 + 3 * col + 1] = accv[3 * i + 1] * RS128;
        selfx[gn + 128 + 3 * col + 2] = accv[3 * i + 2] * RS128;
    }
}

// per-node halves of MLP1: pAB[n][0:32] = s_n @ l0W1[0:128], pAB[n][32:64] = s_n @ l0W1[128:256]
__global__ __launch_bounds__(256) void k_pre(
    const float* __restrict__ prex, const float* __restrict__ l0W1,
    float* __restrict__ pAB) {
    __shared__ float xs[8][128];
    const int t = threadIdx.x;
    const int nb = blockIdx.x * 8;
    for (int idx = t; idx < 8 * 128; idx += 256) {
        int n = idx >> 7, u = idx & 127;
        xs[n][u] = prex[(size_t)(nb + n) * 512 + u];
    }
    __syncthreads();
    const int n = t >> 5, k = t & 31;
    float a = 0, b = 0;
    for (int u = 0; u < 128; ++u) {
        float s = xs[n][u];
        a = fmaf(s, l0W1[u * 32 + k], a);
        b = fmaf(s, l0W1[(128 + u) * 32 + k], b);
    }
    pAB[(size_t)(nb + n) * 64 + k] = a;
    pAB[(size_t)(nb + n) * 64 + 32 + k] = b;
}

// ---- CSR build ----
__global__ __launch_bounds__(256) void k_deg(const int* __restrict__ ei, int* __restrict__ deg) {
    int e = blockIdx.x * 256 + threadIdx.x;
    if (e < EE) atomicAdd(&deg[ei[e]], 1);
}

__global__ __launch_bounds__(1024) void k_scan(const int* __restrict__ deg, int* __restrict__ row_ptr) {
    __shared__ int part[1024];
    const int t = threadIdx.x;
    const int base = t * 10;
    int loc[10];
    int s = 0;
#pragma unroll
    for (int i = 0; i < 10; ++i) {
        int idx = base + i;
        int d = (idx < NN) ? deg[idx] : 0;
        loc[i] = s;
        s += d;
    }
    part[t] = s;
    __syncthreads();
    for (int off = 1; off < 1024; off <<= 1) {
        int v = (t >= off) ? part[t - off] : 0;
        __syncthreads();
        part[t] += v;
        __syncthreads();
    }
    int excl = (t > 0) ? part[t - 1] : 0;
#pragma unroll
    for (int i = 0; i < 10; ++i) {
        int idx = base + i;
        if (idx <= NN) row_ptr[idx] = excl + loc[i];
    }
}

__global__ __launch_bounds__(256) void k_fill(const int* __restrict__ ei,
                                              const int* __restrict__ row_ptr,
                                              int* __restrict__ cursor,
                                              int* __restrict__ csr_eid) {
    int e = blockIdx.x * 256 + threadIdx.x;
    if (e < EE) {
        int d = ei[e];
        int pos = atomicAdd(&cursor[d], 1);
        csr_eid[row_ptr[d] + pos] = e;
    }
}

// ---- per-dst edge compute + aggregate (no atomics) ----
// 512 threads: thread (u = t&127, q = t>>7) owns output column q*128+u of both MLP2s.
__global__ __launch_bounds__(512) void k_gather(
    const float* __restrict__ prex, const float* __restrict__ selfx,
    const float* __restrict__ pAB,
    const int* __restrict__ edge_index, const float* __restrict__ edge_attr,
    const float* __restrict__ edge_sh,
    const int* __restrict__ row_ptr, const int* __restrict__ csr_eid,
    const float* __restrict__ fcnW1, const float* __restrict__ fcnW2,
    const float* __restrict__ l0W1, const float* __restrict__ l0W2,
    float* __restrict__ accb) {
    const int dst = blockIdx.x;
    const int t = threadIdx.x;
    const int beg = row_ptr[dst];
    const int ne = row_ptr[dst + 1] - beg;

    __shared__ float dstv[384];
    __shared__ float pAd[32];
    __shared__ float ip[CH][128];
    __shared__ float ea[CH][32];
    __shared__ __align__(16) float2 hh2[CH * 32];   // {h1, ha} per (edge, k)
    __shared__ float sxl[CH][512];                  // staged selfx rows
    __shared__ float shl[CH][4];
    __shared__ int srcs[CH];
    __shared__ int eidl[CH];
    __shared__ float red[3 * 512];

    for (int i = t; i < 384; i += 512) dstv[i] = prex[(size_t)dst * 512 + 128 + i];
    if (t < 32) pAd[t] = pAB[(size_t)dst * 64 + t];

    const int u = t & 127;
    const int q = t >> 7;    // quarter 0..3, wave-uniform
    float acc0 = 0, acc1 = 0, acc2 = 0, acc3 = 0;
    __syncthreads();

    for (int c0 = 0; c0 < ne; c0 += CH) {
        const int ce = min(CH, ne - c0);
        if (t < CH) {
            int id = csr_eid[beg + c0 + ((t < ce) ? t : 0)];
            eidl[t] = id;
            srcs[t] = edge_index[EE + id];
            const float4 s = *(const float4*)(edge_sh + (size_t)id * 4);
            shl[t][0] = s.x; shl[t][1] = s.y; shl[t][2] = s.z; shl[t][3] = s.w;
        }
        __syncthreads();

        // stage edge_attr, inner products, selfx rows
        for (int idx = t; idx < ce * 32; idx += 512) {
            int e = idx >> 5, j = idx & 31;
            ea[e][j] = edge_attr[(size_t)eidl[e] * 32 + j];
        }
        for (int idx = t; idx < ce * 128; idx += 512) {
            int e = idx >> 7, uu = idx & 127;
            const float* pv = prex + (size_t)srcs[e] * 512 + 128 + 3 * uu;
            ip[e][uu] = (dstv[3 * uu] * pv[0] + dstv[3 * uu + 1] * pv[1] +
                         dstv[3 * uu + 2] * pv[2]) * R3;
        }
        for (int idx = t; idx < ce * 512; idx += 512) {
            int e = idx >> 9, c = idx & 511;
            sxl[e][c] = selfx[(size_t)srcs[e] * 512 + c];
        }
        __syncthreads();

        // hidden units: thread (e = t>>5, k = t&31): h1 (128-FMA) + ha (32-FMA)
        {
            const int e = t >> 5, k = t & 31;
            float2 v = {0.0f, 0.0f};
            if (e < ce) {
                float a0 = pAd[k] + pAB[(size_t)srcs[e] * 64 + 32 + k];
                float a1 = 0, a2 = 0, a3 = 0;
#pragma unroll 8
                for (int j = 0; j < 128; j += 4) {
                    const float4 ipv = *(const float4*)&ip[e][j];
                    a0 = fmaf(ipv.x, l0W1[(256 + j) * 32 + k], a0);
                    a1 = fmaf(ipv.y, l0W1[(257 + j) * 32 + k], a1);
                    a2 = fmaf(ipv.z, l0W1[(258 + j) * 32 + k], a2);
                    a3 = fmaf(ipv.w, l0W1[(259 + j) * 32 + k], a3);
                }
                float c0s = 0, c1s = 0;
#pragma unroll
                for (int j = 0; j < 32; j += 2) {
                    c0s = fmaf(ea[e][j], fcnW1[j * 32 + k], c0s);
                    c1s = fmaf(ea[e][j + 1], fcnW1[(j + 1) * 32 + k], c1s);
                }
                v.x = sspf(((a0 + a1) + (a2 + a3)) * RS384);
                v.y = sspf((c0s + c1s) * RS32);
            }
            hh2[e * 32 + k] = v;
        }
        __syncthreads();

        // phase C: accumulate A,B for all 16 edge slots at column q*128+u.
        // Weights read ONCE per chunk per block (coalesced, no quarter redundancy).
        {
            const int col = (q << 7) + u;
            float A[CH], B[CH];
#pragma unroll
            for (int e = 0; e < CH; ++e) { A[e] = 0; B[e] = 0; }
#pragma unroll 2
            for (int k = 0; k < 32; k += 2) {
                const float wf0 = fcnW2[k * 512 + col];
                const float wf1 = fcnW2[(k + 1) * 512 + col];
                const float wl0 = l0W2[k * 512 + col];
                const float wl1 = l0W2[(k + 1) * 512 + col];
#pragma unroll
                for (int e = 0; e < CH; ++e) {
                    const float4 h = *(const float4*)&hh2[e * 32 + k];  // {h1_k, ha_k, h1_k1, ha_k1}
                    A[e] = fmaf(h.y, wf0, A[e]);
                    A[e] = fmaf(h.w, wf1, A[e]);
                    B[e] = fmaf(h.x, wl0, B[e]);
                    B[e] = fmaf(h.z, wl1, B[e]);
                }
            }
            // separable epilogue: quadrant q adds its own contribution (dead slots give w=0)
            const float inv32 = 1.0f / 32.0f;
            if (q == 0) {
#pragma unroll
                for (int e = 0; e < CH; ++e) {
                    float w1 = A[e] * B[e] * inv32;
                    acc0 = fmaf(0.5f * w1 * shl[e][0], sxl[e][u], acc0);
                }
            } else if (q == 1) {
#pragma unroll
                for (int e = 0; e < CH; ++e) {
                    float w2 = A[e] * B[e] * inv32;
                    float g = C1V * w2 * sxl[e][u];
                    acc1 = fmaf(g, shl[e][1], acc1);
                    acc2 = fmaf(g, shl[e][2], acc2);
                    acc3 = fmaf(g, shl[e][3], acc3);
                }
            } else if (q == 2) {
#pragma unroll
                for (int e = 0; e < CH; ++e) {
                    float w3 = A[e] * B[e] * inv32;
                    float g = C1V * w3 * shl[e][0];
                    acc1 = fmaf(g, sxl[e][128 + 3 * u + 0], acc1);
                    acc2 = fmaf(g, sxl[e][128 + 3 * u + 1], acc2);
                    acc3 = fmaf(g, sxl[e][128 + 3 * u + 2], acc3);
                }
            } else {
#pragma unroll
                for (int e = 0; e < CH; ++e) {
                    float w4 = A[e] * B[e] * inv32;
                    float dv = sxl[e][128 + 3 * u + 0] * shl[e][1] +
                               sxl[e][128 + 3 * u + 1] * shl[e][2] +
                               sxl[e][128 + 3 * u + 2] * shl[e][3];
                    acc0 = fmaf(0.5f * R3 * w4, dv, acc0);
                }
            }
        }
        __syncthreads();
    }

    // cross-quarter reduce, add self_x, store
    if (q > 0) {
        float4 v = {acc0, acc1, acc2, acc3};
        *(float4*)(red + (q - 1) * 512 + 4 * u) = v;
    }
    __syncthreads();
    if (q == 0) {
#pragma unroll
        for (int j = 0; j < 3; ++j) {
            float4 v = *(const float4*)(red + j * 512 + 4 * u);
            acc0 += v.x; acc1 += v.y; acc2 += v.z; acc3 += v.w;
        }
        const size_t g = (size_t)dst * 512;
        accb[g + u] = acc0 + selfx[g + u];
        accb[g + 128 + 3 * u + 0] = acc1 + selfx[g + 128 + 3 * u + 0];
        accb[g + 128 + 3 * u + 1] = acc2 + selfx[g + 128 + 3 * u + 1];
        accb[g + 128 + 3 * u + 2] = acc3 + selfx[g + 128 + 3 * u + 2];
    }
}

extern "C" void kernel_launch(void* const* d_in, const int* in_sizes, int n_in,
                              void* d_out, int out_size, void* d_ws, size_t ws_size,
                              hipStream_t stream) {
    const float* x = (const float*)d_in[0];
    const int* edge_index = (const int*)d_in[1];
    const float* edge_attr = (const float*)d_in[2];
    const float* edge_sh = (const float*)d_in[3];
    const float* Wp0 = (const float*)d_in[4];
    const float* bp0 = (const float*)d_in[5];
    const float* Wp1 = (const float*)d_in[6];
    const float* ngW1 = (const float*)d_in[7];
    const float* ngb1 = (const float*)d_in[8];
    const float* ngW2 = (const float*)d_in[9];
    const float* ngb2 = (const float*)d_in[10];
    const float* Wn0 = (const float*)d_in[11];
    const float* bn0 = (const float*)d_in[12];
    const float* Wn1 = (const float*)d_in[13];
    const float* fcnW1 = (const float*)d_in[14];
    const float* fcnW2 = (const float*)d_in[15];
    const float* l0W1 = (const float*)d_in[16];
    const float* l0W2 = (const float*)d_in[17];
    const float* Wo0 = (const float*)d_in[18];
    const float* bo0 = (const float*)d_in[19];
    const float* Wo1 = (const float*)d_in[20];

    float* out = (float*)d_out;
    float* prex = out;                       // d_out as pre_x scratch (dead before final write)
    float* selfx = (float*)d_ws;
    float* accb = selfx + (size_t)NN * 512;
    int* deg = (int*)(accb + (size_t)NN * 512);
    int* cursor = deg + NN;
    int* row_ptr = cursor + NN;
    int* csr_eid = row_ptr + NN + 1;
    float* pAB = (float*)(csr_eid + EE);

    hipMemsetAsync(deg, 0, 2 * NN * sizeof(int), stream);  // deg + cursor

    k_irrep<<<NN / 16, 256, 0, stream>>>(x, Wp0, bp0, Wp1, prex);
    k_pre<<<NN / 8, 256, 0, stream>>>(prex, l0W1, pAB);
    k_self<<<NN / 16, 256, 0, stream>>>(x, ngW1, ngb1, ngW2, ngb2, Wn0, bn0, Wn1, selfx);
    k_deg<<<EE / 256, 256, 0, stream>>>(edge_index, deg);
    k_scan<<<1, 1024, 0, stream>>>(deg, row_ptr);
    k_fill<<<EE / 256, 256, 0, stream>>>(edge_index, row_ptr, cursor, csr_eid);
    k_gather<<<NN, 512, 0, stream>>>(prex, selfx, pAB, edge_index, edge_attr, edge_sh,
                                     row_ptr, csr_eid, fcnW1, fcnW2, l0W1, l0W2, accb);
    k_irrep<<<NN / 16, 256, 0, stream>>>(accb, Wo0, bo0, Wo1, out);
}

// Round 6
// 779.042 us; speedup vs baseline: 1.6958x; 1.6958x over previous
//
#include <hip/hip_runtime.h>
#include <hip/hip_fp16.h>
#include <math.h>

#define NN 10000
#define EE 160000
#define ECH 8

#define RS128 0.08838834764831845f   // 1/sqrt(128)
#define RS384 0.05103103630798287f   // 1/sqrt(384)
#define RS32  0.17677669529663687f   // 1/sqrt(32)
#define R3    0.57735026918962576f   // 1/sqrt(3)
#define C1V   0.86602540378443865f   // sqrt(3)/2

__device__ __forceinline__ float sspf(float x) {
    return fmaxf(x, 0.0f) + log1pf(__expf(-fabsf(x))) - 0.69314718055994530942f;
}

// out = irrep_linear(X, W0, b0, W1). In-place safe per block (stages tile first).
__global__ __launch_bounds__(256) void k_irrep(
    const float* __restrict__ X, const float* __restrict__ W0,
    const float* __restrict__ b0, const float* __restrict__ W1,
    float* __restrict__ out) {
    __shared__ float xs_t[16][128];
    __shared__ float xv_t[16][384];
    const int t = threadIdx.x;
    const int nb = blockIdx.x * 16;
    for (int idx = t; idx < 16 * 512; idx += 256) {
        int n = idx >> 9, c = idx & 511;
        float v = X[(size_t)(nb + n) * 512 + c];
        if (c < 128) xs_t[n][c] = v; else xv_t[n][c - 128] = v;
    }
    __syncthreads();
    const int col = t & 127, half = t >> 7;
    float accs[8] = {0, 0, 0, 0, 0, 0, 0, 0};
    float accv[24] = {0};
    for (int u = 0; u < 128; ++u) {
        float w0 = W0[u * 128 + col];
        float w1 = W1[u * 128 + col];
#pragma unroll
        for (int i = 0; i < 8; ++i) {
            int n = half * 8 + i;
            accs[i] = fmaf(xs_t[n][u], w0, accs[i]);
            accv[3 * i + 0] = fmaf(xv_t[n][3 * u + 0], w1, accv[3 * i + 0]);
            accv[3 * i + 1] = fmaf(xv_t[n][3 * u + 1], w1, accv[3 * i + 1]);
            accv[3 * i + 2] = fmaf(xv_t[n][3 * u + 2], w1, accv[3 * i + 2]);
        }
    }
    float bias = b0[col];
#pragma unroll
    for (int i = 0; i < 8; ++i) {
        size_t gn = (size_t)(nb + half * 8 + i) * 512;
        out[gn + col] = accs[i] * RS128 + bias;
        out[gn + 128 + 3 * col + 0] = accv[3 * i + 0] * RS128;
        out[gn + 128 + 3 * col + 1] = accv[3 * i + 1] * RS128;
        out[gn + 128 + 3 * col + 2] = accv[3 * i + 2] * RS128;
    }
}

// self_x = irrep_linear(norm_gate(x), Wn0, bn0, Wn1)
__global__ __launch_bounds__(256) void k_self(
    const float* __restrict__ X,
    const float* __restrict__ ngW1, const float* __restrict__ ngb1,
    const float* __restrict__ ngW2, const float* __restrict__ ngb2,
    const float* __restrict__ Wn0, const float* __restrict__ bn0,
    const float* __restrict__ Wn1,
    float* __restrict__ selfx) {
    __shared__ float xv_t[16][384];
    __shared__ float f0_t[16][256];
    __shared__ float t1_t[16][256];
    const int t = threadIdx.x;
    const int nb = blockIdx.x * 16;
    for (int idx = t; idx < 16 * 512; idx += 256) {
        int n = idx >> 9, c = idx & 511;
        float v = X[(size_t)(nb + n) * 512 + c];
        if (c < 128) f0_t[n][c] = v; else xv_t[n][c - 128] = v;
    }
    __syncthreads();
    for (int idx = t; idx < 16 * 128; idx += 256) {
        int n = idx >> 7, u = idx & 127;
        float a = xv_t[n][3 * u], b = xv_t[n][3 * u + 1], c = xv_t[n][3 * u + 2];
        f0_t[n][128 + u] = sqrtf(fmaf(a, a, fmaf(b, b, fmaf(c, c, 1e-12f))));
    }
    __syncthreads();
    {
        float acc[16] = {0};
        for (int k = 0; k < 256; ++k) {
            float w = ngW1[k * 256 + t];
#pragma unroll
            for (int n = 0; n < 16; ++n) acc[n] = fmaf(f0_t[n][k], w, acc[n]);
        }
        float b1 = ngb1[t];
#pragma unroll
        for (int n = 0; n < 16; ++n) {
            float z = acc[n] + b1;
            t1_t[n][t] = z * (1.0f / (1.0f + __expf(-z)));
        }
    }
    __syncthreads();
    {
        float acc[16] = {0};
        for (int k = 0; k < 256; ++k) {
            float w = ngW2[k * 256 + t];
#pragma unroll
            for (int n = 0; n < 16; ++n) acc[n] = fmaf(t1_t[n][k], w, acc[n]);
        }
        float b2 = ngb2[t];
#pragma unroll
        for (int n = 0; n < 16; ++n) f0_t[n][t] = acc[n] + b2;
    }
    __syncthreads();
    for (int idx = t; idx < 16 * 384; idx += 256) {
        int n = idx / 384, j = idx % 384;
        xv_t[n][j] *= f0_t[n][128 + j / 3];
    }
    __syncthreads();
    const int col = t & 127, half = t >> 7;
    float accs[8] = {0, 0, 0, 0, 0, 0, 0, 0};
    float accv[24] = {0};
    for (int u = 0; u < 128; ++u) {
        float w0 = Wn0[u * 128 + col];
        float w1 = Wn1[u * 128 + col];
#pragma unroll
        for (int i = 0; i < 8; ++i) {
            int n = half * 8 + i;
            accs[i] = fmaf(f0_t[n][u], w0, accs[i]);
            accv[3 * i + 0] = fmaf(xv_t[n][3 * u + 0], w1, accv[3 * i + 0]);
            accv[3 * i + 1] = fmaf(xv_t[n][3 * u + 1], w1, accv[3 * i + 1]);
            accv[3 * i + 2] = fmaf(xv_t[n][3 * u + 2], w1, accv[3 * i + 2]);
        }
    }
    float bias = bn0[col];
#pragma unroll
    for (int i = 0; i < 8; ++i) {
        size_t gn = (size_t)(nb + half * 8 + i) * 512;
        selfx[gn + col] = accs[i] * RS128 + bias;
        selfx[gn + 128 + 3 * col + 0] = accv[3 * i + 0] * RS128;
        selfx[gn + 128 + 3 * col + 1] = accv[3 * i + 1] * RS128;
        selfx[gn + 128 + 3 * col + 2] = accv[3 * i + 2] * RS128;
    }
}

// per-node halves of MLP1: pAB[n][0:32] = s_n @ l0W1[0:128], pAB[n][32:64] = s_n @ l0W1[128:256]
__global__ __launch_bounds__(256) void k_pre(
    const float* __restrict__ prex, const float* __restrict__ l0W1,
    float* __restrict__ pAB) {
    __shared__ float xs[8][128];
    const int t = threadIdx.x;
    const int nb = blockIdx.x * 8;
    for (int idx = t; idx < 8 * 128; idx += 256) {
        int n = idx >> 7, u = idx & 127;
        xs[n][u] = prex[(size_t)(nb + n) * 512 + u];
    }
    __syncthreads();
    const int n = t >> 5, k = t & 31;
    float a = 0, b = 0;
    for (int u = 0; u < 128; ++u) {
        float s = xs[n][u];
        a = fmaf(s, l0W1[u * 32 + k], a);
        b = fmaf(s, l0W1[(128 + u) * 32 + k], b);
    }
    pAB[(size_t)(nb + n) * 64 + k] = a;
    pAB[(size_t)(nb + n) * 64 + 32 + k] = b;
}

// ---- CSR build ----
__global__ __launch_bounds__(256) void k_deg(const int* __restrict__ ei, int* __restrict__ deg) {
    int e = blockIdx.x * 256 + threadIdx.x;
    if (e < EE) atomicAdd(&deg[ei[e]], 1);
}

__global__ __launch_bounds__(1024) void k_scan(const int* __restrict__ deg, int* __restrict__ row_ptr) {
    __shared__ int part[1024];
    const int t = threadIdx.x;
    const int base = t * 10;
    int loc[10];
    int s = 0;
#pragma unroll
    for (int i = 0; i < 10; ++i) {
        int idx = base + i;
        int d = (idx < NN) ? deg[idx] : 0;
        loc[i] = s;
        s += d;
    }
    part[t] = s;
    __syncthreads();
    for (int off = 1; off < 1024; off <<= 1) {
        int v = (t >= off) ? part[t - off] : 0;
        __syncthreads();
        part[t] += v;
        __syncthreads();
    }
    int excl = (t > 0) ? part[t - 1] : 0;
#pragma unroll
    for (int i = 0; i < 10; ++i) {
        int idx = base + i;
        if (idx <= NN) row_ptr[idx] = excl + loc[i];
    }
}

__global__ __launch_bounds__(256) void k_fill(const int* __restrict__ ei,
                                              const int* __restrict__ row_ptr,
                                              int* __restrict__ cursor,
                                              int* __restrict__ csr_eid) {
    int e = blockIdx.x * 256 + threadIdx.x;
    if (e < EE) {
        int d = ei[e];
        int pos = atomicAdd(&cursor[d], 1);
        csr_eid[row_ptr[d] + pos] = e;
    }
}

// ---- edge-parallel hidden units: hh[e][0:32]=h1, hh[e][32:64]=ha (fp16) ----
__global__ __launch_bounds__(256) void k_hidden(
    const float* __restrict__ prex, const float* __restrict__ pAB,
    const int* __restrict__ edge_index, const float* __restrict__ edge_attr,
    const float* __restrict__ fcnW1, const float* __restrict__ l0W1,
    __half* __restrict__ hh) {
    const int eb = blockIdx.x * 8;
    const int t = threadIdx.x;
    __shared__ __align__(16) float ip[8][128];
    __shared__ float ea[8][32];
    __shared__ int dsts[8], srcs[8];
    if (t < 8) {
        dsts[t] = edge_index[eb + t];
        srcs[t] = edge_index[EE + eb + t];
    }
    __syncthreads();
    for (int idx = t; idx < 8 * 32; idx += 256) {
        int e = idx >> 5, j = idx & 31;
        ea[e][j] = edge_attr[(size_t)(eb + e) * 32 + j];
    }
    for (int idx = t; idx < 8 * 128; idx += 256) {
        int e = idx >> 7, uu = idx & 127;
        const float* pd = prex + (size_t)dsts[e] * 512 + 128 + 3 * uu;
        const float* ps = prex + (size_t)srcs[e] * 512 + 128 + 3 * uu;
        ip[e][uu] = (pd[0] * ps[0] + pd[1] * ps[1] + pd[2] * ps[2]) * R3;
    }
    __syncthreads();
    const int e = t >> 5, k = t & 31;
    float a0 = pAB[(size_t)dsts[e] * 64 + k] + pAB[(size_t)srcs[e] * 64 + 32 + k];
    float a1 = 0, a2 = 0, a3 = 0;
#pragma unroll 8
    for (int j = 0; j < 128; j += 4) {
        const float4 ipv = *(const float4*)&ip[e][j];
        a0 = fmaf(ipv.x, l0W1[(256 + j) * 32 + k], a0);
        a1 = fmaf(ipv.y, l0W1[(257 + j) * 32 + k], a1);
        a2 = fmaf(ipv.z, l0W1[(258 + j) * 32 + k], a2);
        a3 = fmaf(ipv.w, l0W1[(259 + j) * 32 + k], a3);
    }
    float c0 = 0, c1 = 0;
#pragma unroll
    for (int j = 0; j < 32; j += 2) {
        c0 = fmaf(ea[e][j], fcnW1[j * 32 + k], c0);
        c1 = fmaf(ea[e][j + 1], fcnW1[(j + 1) * 32 + k], c1);
    }
    const float h1v = sspf(((a0 + a1) + (a2 + a3)) * RS384);
    const float hav = sspf((c0 + c1) * RS32);
    hh[(size_t)(eb + e) * 64 + k] = __float2half(h1v);
    hh[(size_t)(eb + e) * 64 + 32 + k] = __float2half(hav);
}

// ---- per-dst accumulate: thread owns one of 512 output cols; MLP2 weights in registers ----
__global__ __launch_bounds__(512) void k_accum(
    const __half* __restrict__ hh, const float* __restrict__ selfx,
    const int* __restrict__ edge_index, const float* __restrict__ edge_sh,
    const int* __restrict__ row_ptr, const int* __restrict__ csr_eid,
    const float* __restrict__ fcnW2, const float* __restrict__ l0W2,
    float* __restrict__ outacc) {
    const int dst = blockIdx.x;
    const int t = threadIdx.x;
    const int beg = row_ptr[dst];
    const int ne = row_ptr[dst + 1] - beg;
    const int u = t & 127;
    const int q = t >> 7;       // quadrant 0..3 (wave-uniform)

    __shared__ __align__(16) float hl[ECH][64];   // {h1[32] | ha[32]} per edge
    __shared__ float shl[ECH][4];
    __shared__ int srcs[ECH];
    __shared__ float red[3 * 512];

    // per-thread weight cache: loaded ONCE per block, coalesced
    float wf[32], wl[32];
#pragma unroll
    for (int k = 0; k < 32; ++k) {
        wf[k] = fcnW2[k * 512 + t];
        wl[k] = l0W2[k * 512 + t];
    }
    float acc0 = 0, acc1 = 0, acc2 = 0, acc3 = 0;

    for (int c0 = 0; c0 < ne; c0 += ECH) {
        const int ce = min(ECH, ne - c0);
        __syncthreads();   // guard LDS reuse from previous chunk
        {
            // stage hh rows: t = e*64 + j, wave-uniform e
            const int e = t >> 6, j = t & 63;
            float v = 0.0f;
            if (e < ce) {
                const int id = csr_eid[beg + c0 + e];
                v = __half2float(hh[(size_t)id * 64 + j]);
            }
            hl[e][j] = v;
        }
        if (t < ECH) {
            const int id = csr_eid[beg + c0 + ((t < ce) ? t : 0)];
            srcs[t] = edge_index[EE + id];
            const float4 s = *(const float4*)(edge_sh + (size_t)id * 4);
            shl[t][0] = s.x; shl[t][1] = s.y; shl[t][2] = s.z; shl[t][3] = s.w;
        }
        __syncthreads();

#pragma unroll
        for (int e = 0; e < ECH; ++e) {
            if (e < ce) {   // block-uniform
                float A = 0, B = 0;
#pragma unroll
                for (int kk = 0; kk < 8; ++kk) {
                    const float4 h1v = *(const float4*)&hl[e][4 * kk];
                    const float4 hav = *(const float4*)&hl[e][32 + 4 * kk];
                    A = fmaf(hav.x, wf[4 * kk + 0], A);
                    A = fmaf(hav.y, wf[4 * kk + 1], A);
                    A = fmaf(hav.z, wf[4 * kk + 2], A);
                    A = fmaf(hav.w, wf[4 * kk + 3], A);
                    B = fmaf(h1v.x, wl[4 * kk + 0], B);
                    B = fmaf(h1v.y, wl[4 * kk + 1], B);
                    B = fmaf(h1v.z, wl[4 * kk + 2], B);
                    B = fmaf(h1v.w, wl[4 * kk + 3], B);
                }
                const float w = A * B * (1.0f / 32.0f);
                const int src = srcs[e];
                const float sh0 = shl[e][0], s1x = shl[e][1], s1y = shl[e][2], s1z = shl[e][3];
                const float* sr = selfx + (size_t)src * 512;
                if (q == 0) {
                    acc0 = fmaf(0.5f * w * sh0, sr[u], acc0);
                } else if (q == 1) {
                    const float g = C1V * w * sr[u];
                    acc1 = fmaf(g, s1x, acc1);
                    acc2 = fmaf(g, s1y, acc2);
                    acc3 = fmaf(g, s1z, acc3);
                } else if (q == 2) {
                    const float g = C1V * w * sh0;
                    acc1 = fmaf(g, sr[128 + 3 * u + 0], acc1);
                    acc2 = fmaf(g, sr[128 + 3 * u + 1], acc2);
                    acc3 = fmaf(g, sr[128 + 3 * u + 2], acc3);
                } else {
                    const float dv = sr[128 + 3 * u + 0] * s1x +
                                     sr[128 + 3 * u + 1] * s1y +
                                     sr[128 + 3 * u + 2] * s1z;
                    acc0 = fmaf(0.5f * R3 * w, dv, acc0);
                }
            }
        }
    }

    // cross-quadrant reduce, add self_x, store
    __syncthreads();
    if (q > 0) {
        float4 v = {acc0, acc1, acc2, acc3};
        *(float4*)(red + (q - 1) * 512 + 4 * u) = v;
    }
    __syncthreads();
    if (q == 0) {
#pragma unroll
        for (int j = 0; j < 3; ++j) {
            float4 v = *(const float4*)(red + j * 512 + 4 * u);
            acc0 += v.x; acc1 += v.y; acc2 += v.z; acc3 += v.w;
        }
        const size_t g = (size_t)dst * 512;
        outacc[g + u] = acc0 + selfx[g + u];
        outacc[g + 128 + 3 * u + 0] = acc1 + selfx[g + 128 + 3 * u + 0];
        outacc[g + 128 + 3 * u + 1] = acc2 + selfx[g + 128 + 3 * u + 1];
        outacc[g + 128 + 3 * u + 2] = acc3 + selfx[g + 128 + 3 * u + 2];
    }
}

extern "C" void kernel_launch(void* const* d_in, const int* in_sizes, int n_in,
                              void* d_out, int out_size, void* d_ws, size_t ws_size,
                              hipStream_t stream) {
    const float* x = (const float*)d_in[0];
    const int* edge_index = (const int*)d_in[1];
    const float* edge_attr = (const float*)d_in[2];
    const float* edge_sh = (const float*)d_in[3];
    const float* Wp0 = (const float*)d_in[4];
    const float* bp0 = (const float*)d_in[5];
    const float* Wp1 = (const float*)d_in[6];
    const float* ngW1 = (const float*)d_in[7];
    const float* ngb1 = (const float*)d_in[8];
    const float* ngW2 = (const float*)d_in[9];
    const float* ngb2 = (const float*)d_in[10];
    const float* Wn0 = (const float*)d_in[11];
    const float* bn0 = (const float*)d_in[12];
    const float* Wn1 = (const float*)d_in[13];
    const float* fcnW1 = (const float*)d_in[14];
    const float* fcnW2 = (const float*)d_in[15];
    const float* l0W1 = (const float*)d_in[16];
    const float* l0W2 = (const float*)d_in[17];
    const float* Wo0 = (const float*)d_in[18];
    const float* bo0 = (const float*)d_in[19];
    const float* Wo1 = (const float*)d_in[20];

    float* out = (float*)d_out;
    float* prex = out;                       // d_out as pre_x scratch; k_accum overwrites it
    float* selfx = (float*)d_ws;
    int* deg = (int*)(selfx + (size_t)NN * 512);
    int* cursor = deg + NN;
    int* row_ptr = cursor + NN;
    int* csr_eid = row_ptr + NN + 1;
    float* pAB = (float*)(csr_eid + EE);
    __half* hh = (__half*)(pAB + (size_t)NN * 64);

    hipMemsetAsync(deg, 0, 2 * NN * sizeof(int), stream);  // deg + cursor

    k_irrep<<<NN / 16, 256, 0, stream>>>(x, Wp0, bp0, Wp1, prex);
    k_pre<<<NN / 8, 256, 0, stream>>>(prex, l0W1, pAB);
    k_self<<<NN / 16, 256, 0, stream>>>(x, ngW1, ngb1, ngW2, ngb2, Wn0, bn0, Wn1, selfx);
    k_deg<<<EE / 256, 256, 0, stream>>>(edge_index, deg);
    k_scan<<<1, 1024, 0, stream>>>(deg, row_ptr);
    k_fill<<<EE / 256, 256, 0, stream>>>(edge_index, row_ptr, cursor, csr_eid);
    k_hidden<<<EE / 8, 256, 0, stream>>>(prex, pAB, edge_index, edge_attr, fcnW1, l0W1, hh);
    k_accum<<<NN, 512, 0, stream>>>(hh, selfx, edge_index, edge_sh, row_ptr, csr_eid,
                                    fcnW2, l0W2, out);
    k_irrep<<<NN / 16, 256, 0, stream>>>(out, Wo0, bo0, Wo1, out);
}

// Round 7
// 551.374 us; speedup vs baseline: 2.3960x; 1.4129x over previous
//
#include <hip/hip_runtime.h>
#include <hip/hip_fp16.h>
#include <math.h>

#define NN 10000
#define EE 160000

#define RS128 0.08838834764831845f   // 1/sqrt(128)
#define RS384 0.05103103630798287f   // 1/sqrt(384)
#define RS32  0.17677669529663687f   // 1/sqrt(32)
#define R3    0.57735026918962576f   // 1/sqrt(3)
#define C1V   0.86602540378443865f   // sqrt(3)/2

typedef _Float16 half8 __attribute__((ext_vector_type(8)));
typedef float f32x4 __attribute__((ext_vector_type(4)));

__device__ __forceinline__ float sspf(float x) {
    return fmaxf(x, 0.0f) + log1pf(__expf(-fabsf(x))) - 0.69314718055994530942f;
}

// out = irrep_linear(X, W0, b0, W1). In-place safe per block (stages tile first).
__global__ __launch_bounds__(256) void k_irrep(
    const float* __restrict__ X, const float* __restrict__ W0,
    const float* __restrict__ b0, const float* __restrict__ W1,
    float* __restrict__ out) {
    __shared__ float xs_t[16][128];
    __shared__ float xv_t[16][384];
    const int t = threadIdx.x;
    const int nb = blockIdx.x * 16;
    for (int idx = t; idx < 16 * 512; idx += 256) {
        int n = idx >> 9, c = idx & 511;
        float v = X[(size_t)(nb + n) * 512 + c];
        if (c < 128) xs_t[n][c] = v; else xv_t[n][c - 128] = v;
    }
    __syncthreads();
    const int col = t & 127, half = t >> 7;
    float accs[8] = {0, 0, 0, 0, 0, 0, 0, 0};
    float accv[24] = {0};
    for (int u = 0; u < 128; ++u) {
        float w0 = W0[u * 128 + col];
        float w1 = W1[u * 128 + col];
#pragma unroll
        for (int i = 0; i < 8; ++i) {
            int n = half * 8 + i;
            accs[i] = fmaf(xs_t[n][u], w0, accs[i]);
            accv[3 * i + 0] = fmaf(xv_t[n][3 * u + 0], w1, accv[3 * i + 0]);
            accv[3 * i + 1] = fmaf(xv_t[n][3 * u + 1], w1, accv[3 * i + 1]);
            accv[3 * i + 2] = fmaf(xv_t[n][3 * u + 2], w1, accv[3 * i + 2]);
        }
    }
    float bias = b0[col];
#pragma unroll
    for (int i = 0; i < 8; ++i) {
        size_t gn = (size_t)(nb + half * 8 + i) * 512;
        out[gn + col] = accs[i] * RS128 + bias;
        out[gn + 128 + 3 * col + 0] = accv[3 * i + 0] * RS128;
        out[gn + 128 + 3 * col + 1] = accv[3 * i + 1] * RS128;
        out[gn + 128 + 3 * col + 2] = accv[3 * i + 2] * RS128;
    }
}

// self_x = irrep_linear(norm_gate(x), Wn0, bn0, Wn1)
__global__ __launch_bounds__(256) void k_self(
    const float* __restrict__ X,
    const float* __restrict__ ngW1, const float* __restrict__ ngb1,
    const float* __restrict__ ngW2, const float* __restrict__ ngb2,
    const float* __restrict__ Wn0, const float* __restrict__ bn0,
    const float* __restrict__ Wn1,
    float* __restrict__ selfx) {
    __shared__ float xv_t[16][384];
    __shared__ float f0_t[16][256];
    __shared__ float t1_t[16][256];
    const int t = threadIdx.x;
    const int nb = blockIdx.x * 16;
    for (int idx = t; idx < 16 * 512; idx += 256) {
        int n = idx >> 9, c = idx & 511;
        float v = X[(size_t)(nb + n) * 512 + c];
        if (c < 128) f0_t[n][c] = v; else xv_t[n][c - 128] = v;
    }
    __syncthreads();
    for (int idx = t; idx < 16 * 128; idx += 256) {
        int n = idx >> 7, u = idx & 127;
        float a = xv_t[n][3 * u], b = xv_t[n][3 * u + 1], c = xv_t[n][3 * u + 2];
        f0_t[n][128 + u] = sqrtf(fmaf(a, a, fmaf(b, b, fmaf(c, c, 1e-12f))));
    }
    __syncthreads();
    {
        float acc[16] = {0};
        for (int k = 0; k < 256; ++k) {
            float w = ngW1[k * 256 + t];
#pragma unroll
            for (int n = 0; n < 16; ++n) acc[n] = fmaf(f0_t[n][k], w, acc[n]);
        }
        float b1 = ngb1[t];
#pragma unroll
        for (int n = 0; n < 16; ++n) {
            float z = acc[n] + b1;
            t1_t[n][t] = z * (1.0f / (1.0f + __expf(-z)));
        }
    }
    __syncthreads();
    {
        float acc[16] = {0};
        for (int k = 0; k < 256; ++k) {
            float w = ngW2[k * 256 + t];
#pragma unroll
            for (int n = 0; n < 16; ++n) acc[n] = fmaf(t1_t[n][k], w, acc[n]);
        }
        float b2 = ngb2[t];
#pragma unroll
        for (int n = 0; n < 16; ++n) f0_t[n][t] = acc[n] + b2;
    }
    __syncthreads();
    for (int idx = t; idx < 16 * 384; idx += 256) {
        int n = idx / 384, j = idx % 384;
        xv_t[n][j] *= f0_t[n][128 + j / 3];
    }
    __syncthreads();
    const int col = t & 127, half = t >> 7;
    float accs[8] = {0, 0, 0, 0, 0, 0, 0, 0};
    float accv[24] = {0};
    for (int u = 0; u < 128; ++u) {
        float w0 = Wn0[u * 128 + col];
        float w1 = Wn1[u * 128 + col];
#pragma unroll
        for (int i = 0; i < 8; ++i) {
            int n = half * 8 + i;
            accs[i] = fmaf(f0_t[n][u], w0, accs[i]);
            accv[3 * i + 0] = fmaf(xv_t[n][3 * u + 0], w1, accv[3 * i + 0]);
            accv[3 * i + 1] = fmaf(xv_t[n][3 * u + 1], w1, accv[3 * i + 1]);
            accv[3 * i + 2] = fmaf(xv_t[n][3 * u + 2], w1, accv[3 * i + 2]);
        }
    }
    float bias = bn0[col];
#pragma unroll
    for (int i = 0; i < 8; ++i) {
        size_t gn = (size_t)(nb + half * 8 + i) * 512;
        selfx[gn + col] = accs[i] * RS128 + bias;
        selfx[gn + 128 + 3 * col + 0] = accv[3 * i + 0] * RS128;
        selfx[gn + 128 + 3 * col + 1] = accv[3 * i + 1] * RS128;
        selfx[gn + 128 + 3 * col + 2] = accv[3 * i + 2] * RS128;
    }
}

// per-node halves of MLP1: pAB[n][0:32] = s_n @ l0W1[0:128], pAB[n][32:64] = s_n @ l0W1[128:256]
__global__ __launch_bounds__(256) void k_pre(
    const float* __restrict__ prex, const float* __restrict__ l0W1,
    float* __restrict__ pAB) {
    __shared__ float xs[8][128];
    const int t = threadIdx.x;
    const int nb = blockIdx.x * 8;
    for (int idx = t; idx < 8 * 128; idx += 256) {
        int n = idx >> 7, u = idx & 127;
        xs[n][u] = prex[(size_t)(nb + n) * 512 + u];
    }
    __syncthreads();
    const int n = t >> 5, k = t & 31;
    float a = 0, b = 0;
    for (int u = 0; u < 128; ++u) {
        float s = xs[n][u];
        a = fmaf(s, l0W1[u * 32 + k], a);
        b = fmaf(s, l0W1[(128 + u) * 32 + k], b);
    }
    pAB[(size_t)(nb + n) * 64 + k] = a;
    pAB[(size_t)(nb + n) * 64 + 32 + k] = b;
}

// convert+transpose MLP2 weights to fp16: W_t[col][k] = W[k*512+col]
__global__ __launch_bounds__(256) void k_wconv(
    const float* __restrict__ fcnW2, const float* __restrict__ l0W2,
    _Float16* __restrict__ Wf_t, _Float16* __restrict__ Wl_t) {
    int idx = blockIdx.x * 256 + threadIdx.x;   // 16384
    int k = idx & 31, c = idx >> 5;
    Wf_t[c * 32 + k] = (_Float16)fcnW2[k * 512 + c];
    Wl_t[c * 32 + k] = (_Float16)l0W2[k * 512 + c];
}

// ---- CSR build ----
__global__ __launch_bounds__(256) void k_deg(const int* __restrict__ ei, int* __restrict__ deg) {
    int e = blockIdx.x * 256 + threadIdx.x;
    if (e < EE) atomicAdd(&deg[ei[e]], 1);
}

__global__ __launch_bounds__(1024) void k_scan(const int* __restrict__ deg, int* __restrict__ row_ptr) {
    __shared__ int part[1024];
    const int t = threadIdx.x;
    const int base = t * 10;
    int loc[10];
    int s = 0;
#pragma unroll
    for (int i = 0; i < 10; ++i) {
        int idx = base + i;
        int d = (idx < NN) ? deg[idx] : 0;
        loc[i] = s;
        s += d;
    }
    part[t] = s;
    __syncthreads();
    for (int off = 1; off < 1024; off <<= 1) {
        int v = (t >= off) ? part[t - off] : 0;
        __syncthreads();
        part[t] += v;
        __syncthreads();
    }
    int excl = (t > 0) ? part[t - 1] : 0;
#pragma unroll
    for (int i = 0; i < 10; ++i) {
        int idx = base + i;
        if (idx <= NN) row_ptr[idx] = excl + loc[i];
    }
}

__global__ __launch_bounds__(256) void k_fill(const int* __restrict__ ei,
                                              const int* __restrict__ row_ptr,
                                              int* __restrict__ cursor,
                                              int* __restrict__ csr_eid) {
    int e = blockIdx.x * 256 + threadIdx.x;
    if (e < EE) {
        int d = ei[e];
        int pos = atomicAdd(&cursor[d], 1);
        csr_eid[row_ptr[d] + pos] = e;
    }
}

// ---- edge-parallel hidden units: hh[e][0:32]=h1, hh[e][32:64]=ha (fp16) ----
__global__ __launch_bounds__(256) void k_hidden(
    const float* __restrict__ prex, const float* __restrict__ pAB,
    const int* __restrict__ edge_index, const float* __restrict__ edge_attr,
    const float* __restrict__ fcnW1, const float* __restrict__ l0W1,
    __half* __restrict__ hh) {
    const int eb = blockIdx.x * 8;
    const int t = threadIdx.x;
    __shared__ __align__(16) float ip[8][128];
    __shared__ float ea[8][32];
    __shared__ int dsts[8], srcs[8];
    if (t < 8) {
        dsts[t] = edge_index[eb + t];
        srcs[t] = edge_index[EE + eb + t];
    }
    __syncthreads();
    for (int idx = t; idx < 8 * 32; idx += 256) {
        int e = idx >> 5, j = idx & 31;
        ea[e][j] = edge_attr[(size_t)(eb + e) * 32 + j];
    }
    for (int idx = t; idx < 8 * 128; idx += 256) {
        int e = idx >> 7, uu = idx & 127;
        const float* pd = prex + (size_t)dsts[e] * 512 + 128 + 3 * uu;
        const float* ps = prex + (size_t)srcs[e] * 512 + 128 + 3 * uu;
        ip[e][uu] = (pd[0] * ps[0] + pd[1] * ps[1] + pd[2] * ps[2]) * R3;
    }
    __syncthreads();
    const int e = t >> 5, k = t & 31;
    float a0 = pAB[(size_t)dsts[e] * 64 + k] + pAB[(size_t)srcs[e] * 64 + 32 + k];
    float a1 = 0, a2 = 0, a3 = 0;
#pragma unroll 8
    for (int j = 0; j < 128; j += 4) {
        const float4 ipv = *(const float4*)&ip[e][j];
        a0 = fmaf(ipv.x, l0W1[(256 + j) * 32 + k], a0);
        a1 = fmaf(ipv.y, l0W1[(257 + j) * 32 + k], a1);
        a2 = fmaf(ipv.z, l0W1[(258 + j) * 32 + k], a2);
        a3 = fmaf(ipv.w, l0W1[(259 + j) * 32 + k], a3);
    }
    float c0 = 0, c1 = 0;
#pragma unroll
    for (int j = 0; j < 32; j += 2) {
        c0 = fmaf(ea[e][j], fcnW1[j * 32 + k], c0);
        c1 = fmaf(ea[e][j + 1], fcnW1[(j + 1) * 32 + k], c1);
    }
    const float h1v = sspf(((a0 + a1) + (a2 + a3)) * RS384);
    const float hav = sspf((c0 + c1) * RS32);
    hh[(size_t)(eb + e) * 64 + k] = __float2half(h1v);
    hh[(size_t)(eb + e) * 64 + 32 + k] = __float2half(hav);
}

// ---- per-dst accumulate via MFMA: per 16-edge chunk, A=Ha@Wf, B=H1@Wl (M=16,K=32,N=512) ----
// 512 threads = 8 waves; wave w owns output cols {q*128 + 16w .. +15} for q=0..3.
__global__ __launch_bounds__(512) void k_accum(
    const __half* __restrict__ hh, const float* __restrict__ selfx,
    const int* __restrict__ edge_index, const float* __restrict__ edge_sh,
    const int* __restrict__ row_ptr, const int* __restrict__ csr_eid,
    const _Float16* __restrict__ Wf_t, const _Float16* __restrict__ Wl_t,
    float* __restrict__ outacc) {
    const int dst = blockIdx.x;
    const int t = threadIdx.x;
    const int lane = t & 63;
    const int wid = t >> 6;          // 0..7
    const int beg = row_ptr[dst];
    const int ne = row_ptr[dst + 1] - beg;

    __shared__ __align__(16) _Float16 h1s[4][16][8];   // [kc][edge][j], k = kc*8+j
    __shared__ __align__(16) _Float16 has[4][16][8];
    __shared__ float shl[16][4];
    __shared__ int srcs[16];
    __shared__ int eidl[16];

    const int lcol = lane & 15;
    const int kg = lane >> 4;        // 0..3
    const int u = 16 * wid + lcol;   // 0..127
    const int koff = kg * 8;

    // B-fragments: loaded once per block (Wf_t/Wl_t are [col][k] fp16)
    half8 bf[4], bl[4];
#pragma unroll
    for (int q = 0; q < 4; ++q) {
        const int col = q * 128 + u;
        bf[q] = *(const half8*)(Wf_t + col * 32 + koff);
        bl[q] = *(const half8*)(Wl_t + col * 32 + koff);
    }

    float acc0 = 0, acc1 = 0, acc2 = 0, acc3 = 0;
    const float inv32 = 1.0f / 32.0f;

    for (int c0 = 0; c0 < ne; c0 += 16) {
        const int ce = min(16, ne - c0);
        __syncthreads();
        if (t < 16) {
            const int id = csr_eid[beg + c0 + ((t < ce) ? t : 0)];
            eidl[t] = id;
            srcs[t] = (t < ce) ? edge_index[EE + id] : 0;
            const float4 s = *(const float4*)(edge_sh + (size_t)id * 4);
            shl[t][0] = s.x; shl[t][1] = s.y; shl[t][2] = s.z; shl[t][3] = s.w;
        }
        __syncthreads();
        {
            // stage hh rows into [kc][e][j] layout; dead slots -> 0
            const int e = t >> 5, w = t & 31;
            const unsigned val = (e < ce) ? ((const unsigned*)hh)[(size_t)eidl[e] * 32 + w] : 0u;
            if (w < 16) ((unsigned*)h1s)[(w >> 2) * 64 + e * 4 + (w & 3)] = val;
            else        ((unsigned*)has)[((w - 16) >> 2) * 64 + e * 4 + ((w - 16) & 3)] = val;
        }
        __syncthreads();

        const half8 haf = *(const half8*)(&has[kg][lcol][0]);
        const half8 h1f = *(const half8*)(&h1s[kg][lcol][0]);
        const f32x4 zero = {0.0f, 0.0f, 0.0f, 0.0f};
        f32x4 A[4], B[4];
#pragma unroll
        for (int q = 0; q < 4; ++q) {
            A[q] = __builtin_amdgcn_mfma_f32_16x16x32_f16(haf, bf[q], zero, 0, 0, 0);
            B[q] = __builtin_amdgcn_mfma_f32_16x16x32_f16(h1f, bl[q], zero, 0, 0, 0);
        }
        // epilogue: lane holds w1..w4 for edges e = kg*4 + r at column u
#pragma unroll
        for (int r = 0; r < 4; ++r) {
            const int e = kg * 4 + r;
            const float w1 = A[0][r] * B[0][r] * inv32;
            const float w2 = A[1][r] * B[1][r] * inv32;
            const float w3 = A[2][r] * B[2][r] * inv32;
            const float w4 = A[3][r] * B[3][r] * inv32;
            const int src = srcs[e];
            const float sh0 = shl[e][0], s1x = shl[e][1], s1y = shl[e][2], s1z = shl[e][3];
            const float* sr = selfx + (size_t)src * 512;
            const float xs0 = sr[u];
            const float* sv = sr + 128 + 3 * u;
            const float xv0 = sv[0], xv1 = sv[1], xv2 = sv[2];
            const float dv = xv0 * s1x + xv1 * s1y + xv2 * s1z;
            acc0 += 0.5f * (w1 * xs0 * sh0 + w4 * dv * R3);
            acc1 += C1V * (w2 * xs0 * s1x + w3 * xv0 * sh0);
            acc2 += C1V * (w2 * xs0 * s1y + w3 * xv1 * sh0);
            acc3 += C1V * (w2 * xs0 * s1z + w3 * xv2 * sh0);
        }
    }

    // butterfly reduce across the 4 kg groups (lanes l, l^16, l^32, l^48 share u)
    acc0 += __shfl_xor(acc0, 16, 64); acc0 += __shfl_xor(acc0, 32, 64);
    acc1 += __shfl_xor(acc1, 16, 64); acc1 += __shfl_xor(acc1, 32, 64);
    acc2 += __shfl_xor(acc2, 16, 64); acc2 += __shfl_xor(acc2, 32, 64);
    acc3 += __shfl_xor(acc3, 16, 64); acc3 += __shfl_xor(acc3, 32, 64);

    if (lane < 16) {
        const size_t g = (size_t)dst * 512;
        outacc[g + u] = acc0 + selfx[g + u];
        outacc[g + 128 + 3 * u + 0] = acc1 + selfx[g + 128 + 3 * u + 0];
        outacc[g + 128 + 3 * u + 1] = acc2 + selfx[g + 128 + 3 * u + 1];
        outacc[g + 128 + 3 * u + 2] = acc3 + selfx[g + 128 + 3 * u + 2];
    }
}

extern "C" void kernel_launch(void* const* d_in, const int* in_sizes, int n_in,
                              void* d_out, int out_size, void* d_ws, size_t ws_size,
                              hipStream_t stream) {
    const float* x = (const float*)d_in[0];
    const int* edge_index = (const int*)d_in[1];
    const float* edge_attr = (const float*)d_in[2];
    const float* edge_sh = (const float*)d_in[3];
    const float* Wp0 = (const float*)d_in[4];
    const float* bp0 = (const float*)d_in[5];
    const float* Wp1 = (const float*)d_in[6];
    const float* ngW1 = (const float*)d_in[7];
    const float* ngb1 = (const float*)d_in[8];
    const float* ngW2 = (const float*)d_in[9];
    const float* ngb2 = (const float*)d_in[10];
    const float* Wn0 = (const float*)d_in[11];
    const float* bn0 = (const float*)d_in[12];
    const float* Wn1 = (const float*)d_in[13];
    const float* fcnW1 = (const float*)d_in[14];
    const float* fcnW2 = (const float*)d_in[15];
    const float* l0W1 = (const float*)d_in[16];
    const float* l0W2 = (const float*)d_in[17];
    const float* Wo0 = (const float*)d_in[18];
    const float* bo0 = (const float*)d_in[19];
    const float* Wo1 = (const float*)d_in[20];

    float* out = (float*)d_out;
    float* prex = out;                       // d_out as pre_x scratch; k_accum overwrites it
    float* selfx = (float*)d_ws;
    int* deg = (int*)(selfx + (size_t)NN * 512);
    int* cursor = deg + NN;
    int* row_ptr = cursor + NN;
    int* csr_eid = row_ptr + NN + 1;
    float* pAB = (float*)(csr_eid + EE);
    __half* hh = (__half*)(pAB + (size_t)NN * 64);
    _Float16* Wf_t = (_Float16*)(hh + (size_t)EE * 64);
    _Float16* Wl_t = Wf_t + 512 * 32;

    hipMemsetAsync(deg, 0, 2 * NN * sizeof(int), stream);  // deg + cursor

    k_irrep<<<NN / 16, 256, 0, stream>>>(x, Wp0, bp0, Wp1, prex);
    k_pre<<<NN / 8, 256, 0, stream>>>(prex, l0W1, pAB);
    k_wconv<<<64, 256, 0, stream>>>(fcnW2, l0W2, Wf_t, Wl_t);
    k_self<<<NN / 16, 256, 0, stream>>>(x, ngW1, ngb1, ngW2, ngb2, Wn0, bn0, Wn1, selfx);
    k_deg<<<EE / 256, 256, 0, stream>>>(edge_index, deg);
    k_scan<<<1, 1024, 0, stream>>>(deg, row_ptr);
    k_fill<<<EE / 256, 256, 0, stream>>>(edge_index, row_ptr, cursor, csr_eid);
    k_hidden<<<EE / 8, 256, 0, stream>>>(prex, pAB, edge_index, edge_attr, fcnW1, l0W1, hh);
    k_accum<<<NN, 512, 0, stream>>>(hh, selfx, edge_index, edge_sh, row_ptr, csr_eid,
                                    Wf_t, Wl_t, out);
    k_irrep<<<NN / 16, 256, 0, stream>>>(out, Wo0, bo0, Wo1, out);
}

// Round 8
// 361.745 us; speedup vs baseline: 3.6520x; 1.5242x over previous
//
#include <hip/hip_runtime.h>
#include <hip/hip_fp16.h>
#include <math.h>

#define NN 10000
#define EE 160000

#define RS128 0.08838834764831845f   // 1/sqrt(128)
#define RS384 0.05103103630798287f   // 1/sqrt(384)
#define RS32  0.17677669529663687f   // 1/sqrt(32)
#define R3    0.57735026918962576f   // 1/sqrt(3)
#define C1V   0.86602540378443865f   // sqrt(3)/2

typedef _Float16 half8 __attribute__((ext_vector_type(8)));
typedef float f32x4 __attribute__((ext_vector_type(4)));

__device__ __forceinline__ float sspf(float x) {
    return fmaxf(x, 0.0f) + log1pf(__expf(-fabsf(x))) - 0.69314718055994530942f;
}

// ---- pack W[K][N] fp32 -> fragment-ordered fp16: P[((ct*KS+ks)*64+lane)*8+j] = W[k][c]
// k = ks*32 + (lane>>4)*8 + j ; c = ct*16 + (lane&15) ; KS = K/32
__global__ __launch_bounds__(256) void k_pack(
    const float* __restrict__ W, _Float16* __restrict__ P, int K, int N) {
    int idx = blockIdx.x * 256 + threadIdx.x;
    if (idx >= K * N) return;
    const int KS = K >> 5;
    int j = idx & 7, lane = (idx >> 3) & 63, rest = idx >> 9;
    int ks = rest % KS, ct = rest / KS;
    int k = ks * 32 + ((lane >> 4) << 3) + j;
    int c = ct * 16 + (lane & 15);
    P[idx] = (_Float16)W[k * N + c];
}

// ---- MFMA irrep_linear: 16 nodes/block, 4 waves (wave w: mat w = s,vx,vy,vz). In-place safe.
__global__ __launch_bounds__(256) void k_irrep_m(
    const float* __restrict__ X, const _Float16* __restrict__ pW0,
    const float* __restrict__ b0, const _Float16* __restrict__ pW1,
    float* __restrict__ out) {
    __shared__ _Float16 Xr[4][16][136];   // [mat][node][k], +8 pad
    const int t = threadIdx.x, lane = t & 63, w = t >> 6;
    const int nb = blockIdx.x * 16;
    for (int idx = t; idx < 16 * 128; idx += 256) {
        int n = idx >> 7, c4 = idx & 127;
        const float4 v = *(const float4*)(X + (size_t)(nb + n) * 512 + 4 * c4);
        float vals[4] = {v.x, v.y, v.z, v.w};
        int c = 4 * c4;
#pragma unroll
        for (int j = 0; j < 4; ++j) {
            int cc = c + j;
            if (cc < 128) Xr[0][n][cc] = (_Float16)vals[j];
            else { int d = cc - 128; Xr[1 + d % 3][n][d / 3] = (_Float16)vals[j]; }
        }
    }
    __syncthreads();
    const _Float16* pW = (w == 0) ? pW0 : pW1;
    const int row16 = lane & 15, kg = lane >> 4;
    f32x4 acc[8];
    const f32x4 zero = {0.0f, 0.0f, 0.0f, 0.0f};
#pragma unroll
    for (int ct = 0; ct < 8; ++ct) acc[ct] = zero;
    for (int ks = 0; ks < 4; ++ks) {
        const half8 a = *(const half8*)&Xr[w][row16][ks * 32 + kg * 8];
#pragma unroll
        for (int ct = 0; ct < 8; ++ct) {
            const half8 b = *(const half8*)(pW + (((ct * 4 + ks) * 64 + lane) << 3));
            acc[ct] = __builtin_amdgcn_mfma_f32_16x16x32_f16(a, b, acc[ct], 0, 0, 0);
        }
    }
#pragma unroll
    for (int ct = 0; ct < 8; ++ct) {
        const int col = ct * 16 + row16;
        const float bb = (w == 0) ? b0[col] : 0.0f;
#pragma unroll
        for (int r = 0; r < 4; ++r) {
            const int node = nb + kg * 4 + r;
            const float val = acc[ct][r] * RS128 + bb;
            if (w == 0) out[(size_t)node * 512 + col] = val;
            else out[(size_t)node * 512 + 128 + 3 * col + (w - 1)] = val;
        }
    }
}

// ---- MFMA fused norm_gate + irrep_linear(Wn) ----
__global__ __launch_bounds__(256) void k_self_m(
    const float* __restrict__ X,
    const _Float16* __restrict__ png1, const float* __restrict__ ngb1,
    const _Float16* __restrict__ png2, const float* __restrict__ ngb2,
    const _Float16* __restrict__ pWn0, const float* __restrict__ bn0,
    const _Float16* __restrict__ pWn1,
    float* __restrict__ selfx) {
    __shared__ _Float16 f0h[16][264];     // f0, later g
    __shared__ _Float16 t1h[16][264];
    __shared__ _Float16 xvh[3][16][136];
    const int t = threadIdx.x, lane = t & 63, w = t >> 6;
    const int nb = blockIdx.x * 16;
    const int row16 = lane & 15, kg = lane >> 4;
    const f32x4 zero = {0.0f, 0.0f, 0.0f, 0.0f};

    for (int idx = t; idx < 16 * 128; idx += 256) {
        int n = idx >> 7, c4 = idx & 127;
        const float4 v = *(const float4*)(X + (size_t)(nb + n) * 512 + 4 * c4);
        float vals[4] = {v.x, v.y, v.z, v.w};
        int c = 4 * c4;
#pragma unroll
        for (int j = 0; j < 4; ++j) {
            int cc = c + j;
            if (cc < 128) f0h[n][cc] = (_Float16)vals[j];
            else { int d = cc - 128; xvh[d % 3][n][d / 3] = (_Float16)vals[j]; }
        }
    }
    __syncthreads();
    for (int idx = t; idx < 16 * 128; idx += 256) {
        int n = idx >> 7, u = idx & 127;
        float a = (float)xvh[0][n][u], b = (float)xvh[1][n][u], c = (float)xvh[2][n][u];
        f0h[n][128 + u] = (_Float16)sqrtf(fmaf(a, a, fmaf(b, b, fmaf(c, c, 1e-12f))));
    }
    __syncthreads();
    // MLP1: t1 = silu(f0 @ ngW1 + b1); wave w owns cols 64w..64w+63
    {
        f32x4 acc[4];
#pragma unroll
        for (int i = 0; i < 4; ++i) acc[i] = zero;
        for (int ks = 0; ks < 8; ++ks) {
            const half8 a = *(const half8*)&f0h[row16][ks * 32 + kg * 8];
#pragma unroll
            for (int c2 = 0; c2 < 4; ++c2) {
                const int ct = 4 * w + c2;
                const half8 b = *(const half8*)(png1 + (((ct * 8 + ks) * 64 + lane) << 3));
                acc[c2] = __builtin_amdgcn_mfma_f32_16x16x32_f16(a, b, acc[c2], 0, 0, 0);
            }
        }
#pragma unroll
        for (int c2 = 0; c2 < 4; ++c2) {
            const int col = (4 * w + c2) * 16 + row16;
            const float bb = ngb1[col];
#pragma unroll
            for (int r = 0; r < 4; ++r) {
                const float z = acc[c2][r] + bb;
                t1h[kg * 4 + r][col] = (_Float16)(z / (1.0f + __expf(-z)));
            }
        }
    }
    __syncthreads();
    // MLP2: g = t1 @ ngW2 + b2 -> f0h
    {
        f32x4 acc[4];
#pragma unroll
        for (int i = 0; i < 4; ++i) acc[i] = zero;
        for (int ks = 0; ks < 8; ++ks) {
            const half8 a = *(const half8*)&t1h[row16][ks * 32 + kg * 8];
#pragma unroll
            for (int c2 = 0; c2 < 4; ++c2) {
                const int ct = 4 * w + c2;
                const half8 b = *(const half8*)(png2 + (((ct * 8 + ks) * 64 + lane) << 3));
                acc[c2] = __builtin_amdgcn_mfma_f32_16x16x32_f16(a, b, acc[c2], 0, 0, 0);
            }
        }
        __syncthreads();   // f0h reads (MLP1 A) done; safe to overwrite
#pragma unroll
        for (int c2 = 0; c2 < 4; ++c2) {
            const int col = (4 * w + c2) * 16 + row16;
            const float bb = ngb2[col];
#pragma unroll
            for (int r = 0; r < 4; ++r)
                f0h[kg * 4 + r][col] = (_Float16)(acc[c2][r] + bb);
        }
    }
    __syncthreads();
    // gate vectors
    for (int idx = t; idx < 16 * 128; idx += 256) {
        int n = idx >> 7, u = idx & 127;
        const _Float16 g = f0h[n][128 + u];
        xvh[0][n][u] = xvh[0][n][u] * g;
        xvh[1][n][u] = xvh[1][n][u] * g;
        xvh[2][n][u] = xvh[2][n][u] * g;
    }
    __syncthreads();
    // final irrep with Wn: wave w -> mat w
    {
        const _Float16* pw = (w == 0) ? pWn0 : pWn1;
        f32x4 acc[8];
#pragma unroll
        for (int ct = 0; ct < 8; ++ct) acc[ct] = zero;
        for (int ks = 0; ks < 4; ++ks) {
            const half8 a = (w == 0)
                ? *(const half8*)&f0h[row16][ks * 32 + kg * 8]
                : *(const half8*)&xvh[w - 1][row16][ks * 32 + kg * 8];
#pragma unroll
            for (int ct = 0; ct < 8; ++ct) {
                const half8 b = *(const half8*)(pw + (((ct * 4 + ks) * 64 + lane) << 3));
                acc[ct] = __builtin_amdgcn_mfma_f32_16x16x32_f16(a, b, acc[ct], 0, 0, 0);
            }
        }
#pragma unroll
        for (int ct = 0; ct < 8; ++ct) {
            const int col = ct * 16 + row16;
            const float bb = (w == 0) ? bn0[col] : 0.0f;
#pragma unroll
            for (int r = 0; r < 4; ++r) {
                const int node = nb + kg * 4 + r;
                const float val = acc[ct][r] * RS128 + bb;
                if (w == 0) selfx[(size_t)node * 512 + col] = val;
                else selfx[(size_t)node * 512 + 128 + 3 * col + (w - 1)] = val;
            }
        }
    }
}

// per-node halves of MLP1: pAB[n][0:32] = s_n @ l0W1[0:128], pAB[n][32:64] = s_n @ l0W1[128:256]
__global__ __launch_bounds__(256) void k_pre(
    const float* __restrict__ prex, const float* __restrict__ l0W1,
    float* __restrict__ pAB) {
    __shared__ float xs[8][128];
    const int t = threadIdx.x;
    const int nb = blockIdx.x * 8;
    for (int idx = t; idx < 8 * 128; idx += 256) {
        int n = idx >> 7, u = idx & 127;
        xs[n][u] = prex[(size_t)(nb + n) * 512 + u];
    }
    __syncthreads();
    const int n = t >> 5, k = t & 31;
    float a = 0, b = 0;
    for (int u = 0; u < 128; ++u) {
        float s = xs[n][u];
        a = fmaf(s, l0W1[u * 32 + k], a);
        b = fmaf(s, l0W1[(128 + u) * 32 + k], b);
    }
    pAB[(size_t)(nb + n) * 64 + k] = a;
    pAB[(size_t)(nb + n) * 64 + 32 + k] = b;
}

// convert+transpose edge-MLP2 weights to fp16: W_t[col][k] = W[k*512+col]
__global__ __launch_bounds__(256) void k_wconv(
    const float* __restrict__ fcnW2, const float* __restrict__ l0W2,
    _Float16* __restrict__ Wf_t, _Float16* __restrict__ Wl_t) {
    int idx = blockIdx.x * 256 + threadIdx.x;   // 16384
    int k = idx & 31, c = idx >> 5;
    Wf_t[c * 32 + k] = (_Float16)fcnW2[k * 512 + c];
    Wl_t[c * 32 + k] = (_Float16)l0W2[k * 512 + c];
}

// ---- CSR build ----
__global__ __launch_bounds__(256) void k_deg(const int* __restrict__ ei, int* __restrict__ deg) {
    int e = blockIdx.x * 256 + threadIdx.x;
    if (e < EE) atomicAdd(&deg[ei[e]], 1);
}

__global__ __launch_bounds__(1024) void k_scan(const int* __restrict__ deg, int* __restrict__ row_ptr) {
    __shared__ int part[1024];
    const int t = threadIdx.x;
    const int base = t * 10;
    int loc[10];
    int s = 0;
#pragma unroll
    for (int i = 0; i < 10; ++i) {
        int idx = base + i;
        int d = (idx < NN) ? deg[idx] : 0;
        loc[i] = s;
        s += d;
    }
    part[t] = s;
    __syncthreads();
    for (int off = 1; off < 1024; off <<= 1) {
        int v = (t >= off) ? part[t - off] : 0;
        __syncthreads();
        part[t] += v;
        __syncthreads();
    }
    int excl = (t > 0) ? part[t - 1] : 0;
#pragma unroll
    for (int i = 0; i < 10; ++i) {
        int idx = base + i;
        if (idx <= NN) row_ptr[idx] = excl + loc[i];
    }
}

__global__ __launch_bounds__(256) void k_fill(const int* __restrict__ ei,
                                              const int* __restrict__ row_ptr,
                                              int* __restrict__ cursor,
                                              int* __restrict__ csr_eid) {
    int e = blockIdx.x * 256 + threadIdx.x;
    if (e < EE) {
        int d = ei[e];
        int pos = atomicAdd(&cursor[d], 1);
        csr_eid[row_ptr[d] + pos] = e;
    }
}

// ---- edge-parallel hidden units: hh[e][0:32]=h1, hh[e][32:64]=ha (fp16) ----
__global__ __launch_bounds__(256) void k_hidden(
    const float* __restrict__ prex, const float* __restrict__ pAB,
    const int* __restrict__ edge_index, const float* __restrict__ edge_attr,
    const float* __restrict__ fcnW1, const float* __restrict__ l0W1,
    __half* __restrict__ hh) {
    const int eb = blockIdx.x * 8;
    const int t = threadIdx.x;
    __shared__ __align__(16) float ip[8][128];
    __shared__ float ea[8][32];
    __shared__ int dsts[8], srcs[8];
    if (t < 8) {
        dsts[t] = edge_index[eb + t];
        srcs[t] = edge_index[EE + eb + t];
    }
    __syncthreads();
    for (int idx = t; idx < 8 * 32; idx += 256) {
        int e = idx >> 5, j = idx & 31;
        ea[e][j] = edge_attr[(size_t)(eb + e) * 32 + j];
    }
    for (int idx = t; idx < 8 * 128; idx += 256) {
        int e = idx >> 7, uu = idx & 127;
        const float* pd = prex + (size_t)dsts[e] * 512 + 128 + 3 * uu;
        const float* ps = prex + (size_t)srcs[e] * 512 + 128 + 3 * uu;
        ip[e][uu] = (pd[0] * ps[0] + pd[1] * ps[1] + pd[2] * ps[2]) * R3;
    }
    __syncthreads();
    const int e = t >> 5, k = t & 31;
    float a0 = pAB[(size_t)dsts[e] * 64 + k] + pAB[(size_t)srcs[e] * 64 + 32 + k];
    float a1 = 0, a2 = 0, a3 = 0;
#pragma unroll 8
    for (int j = 0; j < 128; j += 4) {
        const float4 ipv = *(const float4*)&ip[e][j];
        a0 = fmaf(ipv.x, l0W1[(256 + j) * 32 + k], a0);
        a1 = fmaf(ipv.y, l0W1[(257 + j) * 32 + k], a1);
        a2 = fmaf(ipv.z, l0W1[(258 + j) * 32 + k], a2);
        a3 = fmaf(ipv.w, l0W1[(259 + j) * 32 + k], a3);
    }
    float c0 = 0, c1 = 0;
#pragma unroll
    for (int j = 0; j < 32; j += 2) {
        c0 = fmaf(ea[e][j], fcnW1[j * 32 + k], c0);
        c1 = fmaf(ea[e][j + 1], fcnW1[(j + 1) * 32 + k], c1);
    }
    const float h1v = sspf(((a0 + a1) + (a2 + a3)) * RS384);
    const float hav = sspf((c0 + c1) * RS32);
    hh[(size_t)(eb + e) * 64 + k] = __float2half(h1v);
    hh[(size_t)(eb + e) * 64 + 32 + k] = __float2half(hav);
}

// ---- per-dst accumulate via MFMA ----
__global__ __launch_bounds__(512) void k_accum(
    const __half* __restrict__ hh, const float* __restrict__ selfx,
    const int* __restrict__ edge_index, const float* __restrict__ edge_sh,
    const int* __restrict__ row_ptr, const int* __restrict__ csr_eid,
    const _Float16* __restrict__ Wf_t, const _Float16* __restrict__ Wl_t,
    float* __restrict__ outacc) {
    const int dst = blockIdx.x;
    const int t = threadIdx.x;
    const int lane = t & 63;
    const int wid = t >> 6;          // 0..7
    const int beg = row_ptr[dst];
    const int ne = row_ptr[dst + 1] - beg;

    __shared__ __align__(16) _Float16 h1s[4][16][8];   // [kc][edge][j], k = kc*8+j
    __shared__ __align__(16) _Float16 has[4][16][8];
    __shared__ float shl[16][4];
    __shared__ int srcs[16];
    __shared__ int eidl[16];

    const int lcol = lane & 15;
    const int kg = lane >> 4;        // 0..3
    const int u = 16 * wid + lcol;   // 0..127
    const int koff = kg * 8;

    half8 bf[4], bl[4];
#pragma unroll
    for (int q = 0; q < 4; ++q) {
        const int col = q * 128 + u;
        bf[q] = *(const half8*)(Wf_t + col * 32 + koff);
        bl[q] = *(const half8*)(Wl_t + col * 32 + koff);
    }

    float acc0 = 0, acc1 = 0, acc2 = 0, acc3 = 0;
    const float inv32 = 1.0f / 32.0f;

    for (int c0 = 0; c0 < ne; c0 += 16) {
        const int ce = min(16, ne - c0);
        __syncthreads();
        if (t < 16) {
            const int id = csr_eid[beg + c0 + ((t < ce) ? t : 0)];
            eidl[t] = id;
            srcs[t] = (t < ce) ? edge_index[EE + id] : 0;
            const float4 s = *(const float4*)(edge_sh + (size_t)id * 4);
            shl[t][0] = s.x; shl[t][1] = s.y; shl[t][2] = s.z; shl[t][3] = s.w;
        }
        __syncthreads();
        {
            const int e = t >> 5, w = t & 31;
            const unsigned val = (e < ce) ? ((const unsigned*)hh)[(size_t)eidl[e] * 32 + w] : 0u;
            if (w < 16) ((unsigned*)h1s)[(w >> 2) * 64 + e * 4 + (w & 3)] = val;
            else        ((unsigned*)has)[((w - 16) >> 2) * 64 + e * 4 + ((w - 16) & 3)] = val;
        }
        __syncthreads();

        const half8 haf = *(const half8*)(&has[kg][lcol][0]);
        const half8 h1f = *(const half8*)(&h1s[kg][lcol][0]);
        const f32x4 zero = {0.0f, 0.0f, 0.0f, 0.0f};
        f32x4 A[4], B[4];
#pragma unroll
        for (int q = 0; q < 4; ++q) {
            A[q] = __builtin_amdgcn_mfma_f32_16x16x32_f16(haf, bf[q], zero, 0, 0, 0);
            B[q] = __builtin_amdgcn_mfma_f32_16x16x32_f16(h1f, bl[q], zero, 0, 0, 0);
        }
#pragma unroll
        for (int r = 0; r < 4; ++r) {
            const int e = kg * 4 + r;
            const float w1 = A[0][r] * B[0][r] * inv32;
            const float w2 = A[1][r] * B[1][r] * inv32;
            const float w3 = A[2][r] * B[2][r] * inv32;
            const float w4 = A[3][r] * B[3][r] * inv32;
            const int src = srcs[e];
            const float sh0 = shl[e][0], s1x = shl[e][1], s1y = shl[e][2], s1z = shl[e][3];
            const float* sr = selfx + (size_t)src * 512;
            const float xs0 = sr[u];
            const float* sv = sr + 128 + 3 * u;
            const float xv0 = sv[0], xv1 = sv[1], xv2 = sv[2];
            const float dv = xv0 * s1x + xv1 * s1y + xv2 * s1z;
            acc0 += 0.5f * (w1 * xs0 * sh0 + w4 * dv * R3);
            acc1 += C1V * (w2 * xs0 * s1x + w3 * xv0 * sh0);
            acc2 += C1V * (w2 * xs0 * s1y + w3 * xv1 * sh0);
            acc3 += C1V * (w2 * xs0 * s1z + w3 * xv2 * sh0);
        }
    }

    acc0 += __shfl_xor(acc0, 16, 64); acc0 += __shfl_xor(acc0, 32, 64);
    acc1 += __shfl_xor(acc1, 16, 64); acc1 += __shfl_xor(acc1, 32, 64);
    acc2 += __shfl_xor(acc2, 16, 64); acc2 += __shfl_xor(acc2, 32, 64);
    acc3 += __shfl_xor(acc3, 16, 64); acc3 += __shfl_xor(acc3, 32, 64);

    if (lane < 16) {
        const size_t g = (size_t)dst * 512;
        outacc[g + u] = acc0 + selfx[g + u];
        outacc[g + 128 + 3 * u + 0] = acc1 + selfx[g + 128 + 3 * u + 0];
        outacc[g + 128 + 3 * u + 1] = acc2 + selfx[g + 128 + 3 * u + 1];
        outacc[g + 128 + 3 * u + 2] = acc3 + selfx[g + 128 + 3 * u + 2];
    }
}

extern "C" void kernel_launch(void* const* d_in, const int* in_sizes, int n_in,
                              void* d_out, int out_size, void* d_ws, size_t ws_size,
                              hipStream_t stream) {
    const float* x = (const float*)d_in[0];
    const int* edge_index = (const int*)d_in[1];
    const float* edge_attr = (const float*)d_in[2];
    const float* edge_sh = (const float*)d_in[3];
    const float* Wp0 = (const float*)d_in[4];
    const float* bp0 = (const float*)d_in[5];
    const float* Wp1 = (const float*)d_in[6];
    const float* ngW1 = (const float*)d_in[7];
    const float* ngb1 = (const float*)d_in[8];
    const float* ngW2 = (const float*)d_in[9];
    const float* ngb2 = (const float*)d_in[10];
    const float* Wn0 = (const float*)d_in[11];
    const float* bn0 = (const float*)d_in[12];
    const float* Wn1 = (const float*)d_in[13];
    const float* fcnW1 = (const float*)d_in[14];
    const float* fcnW2 = (const float*)d_in[15];
    const float* l0W1 = (const float*)d_in[16];
    const float* l0W2 = (const float*)d_in[17];
    const float* Wo0 = (const float*)d_in[18];
    const float* bo0 = (const float*)d_in[19];
    const float* Wo1 = (const float*)d_in[20];

    float* out = (float*)d_out;
    float* prex = out;                       // d_out as pre_x scratch; k_accum overwrites it
    float* selfx = (float*)d_ws;
    int* deg = (int*)(selfx + (size_t)NN * 512);
    int* cursor = deg + NN;
    int* row_ptr = cursor + NN;
    int* csr_eid = row_ptr + NN + 1;
    float* pAB = (float*)(csr_eid + EE);
    __half* hh = (__half*)(pAB + (size_t)NN * 64);
    _Float16* Wf_t = (_Float16*)(hh + (size_t)EE * 64);
    _Float16* Wl_t = Wf_t + 512 * 32;
    _Float16* pWp0 = Wl_t + 512 * 32;
    _Float16* pWp1 = pWp0 + 128 * 128;
    _Float16* pWn0 = pWp1 + 128 * 128;
    _Float16* pWn1 = pWn0 + 128 * 128;
    _Float16* pWo0 = pWn1 + 128 * 128;
    _Float16* pWo1 = pWo0 + 128 * 128;
    _Float16* png1 = pWo1 + 128 * 128;
    _Float16* png2 = png1 + 256 * 256;

    hipMemsetAsync(deg, 0, 2 * NN * sizeof(int), stream);  // deg + cursor

    k_pack<<<64, 256, 0, stream>>>(Wp0, pWp0, 128, 128);
    k_pack<<<64, 256, 0, stream>>>(Wp1, pWp1, 128, 128);
    k_pack<<<64, 256, 0, stream>>>(Wn0, pWn0, 128, 128);
    k_pack<<<64, 256, 0, stream>>>(Wn1, pWn1, 128, 128);
    k_pack<<<64, 256, 0, stream>>>(Wo0, pWo0, 128, 128);
    k_pack<<<64, 256, 0, stream>>>(Wo1, pWo1, 128, 128);
    k_pack<<<256, 256, 0, stream>>>(ngW1, png1, 256, 256);
    k_pack<<<256, 256, 0, stream>>>(ngW2, png2, 256, 256);
    k_wconv<<<64, 256, 0, stream>>>(fcnW2, l0W2, Wf_t, Wl_t);

    k_irrep_m<<<NN / 16, 256, 0, stream>>>(x, pWp0, bp0, pWp1, prex);
    k_pre<<<NN / 8, 256, 0, stream>>>(prex, l0W1, pAB);
    k_self_m<<<NN / 16, 256, 0, stream>>>(x, png1, ngb1, png2, ngb2, pWn0, bn0, pWn1, selfx);
    k_deg<<<EE / 256, 256, 0, stream>>>(edge_index, deg);
    k_scan<<<1, 1024, 0, stream>>>(deg, row_ptr);
    k_fill<<<EE / 256, 256, 0, stream>>>(edge_index, row_ptr, cursor, csr_eid);
    k_hidden<<<EE / 8, 256, 0, stream>>>(prex, pAB, edge_index, edge_attr, fcnW1, l0W1, hh);
    k_accum<<<NN, 512, 0, stream>>>(hh, selfx, edge_index, edge_sh, row_ptr, csr_eid,
                                    Wf_t, Wl_t, out);
    k_irrep_m<<<NN / 16, 256, 0, stream>>>(out, pWo0, bo0, pWo1, out);
}

// Round 9
// 294.184 us; speedup vs baseline: 4.4907x; 1.2297x over previous
//
#include <hip/hip_runtime.h>
#include <hip/hip_fp16.h>
#include <math.h>

#define NN 10000
#define EE 160000

#define RS128 0.08838834764831845f   // 1/sqrt(128)
#define RS384 0.05103103630798287f   // 1/sqrt(384)
#define RS32  0.17677669529663687f   // 1/sqrt(32)
#define R3    0.57735026918962576f   // 1/sqrt(3)
#define C1V   0.86602540378443865f   // sqrt(3)/2

typedef _Float16 half8 __attribute__((ext_vector_type(8)));
typedef float f32x4 __attribute__((ext_vector_type(4)));

__device__ __forceinline__ float sspf(float x) {
    return fmaxf(x, 0.0f) + log1pf(__expf(-fabsf(x))) - 0.69314718055994530942f;
}

// ---- pack W[K][N] fp32 -> fragment-ordered fp16: P[((ct*KS+ks)*64+lane)*8+j] = W[k][c]
// k = ks*32 + (lane>>4)*8 + j ; c = ct*16 + (lane&15) ; KS = K/32
__global__ __launch_bounds__(256) void k_pack(
    const float* __restrict__ W, _Float16* __restrict__ P, int K, int N) {
    int idx = blockIdx.x * 256 + threadIdx.x;
    if (idx >= K * N) return;
    const int KS = K >> 5;
    int j = idx & 7, lane = (idx >> 3) & 63, rest = idx >> 9;
    int ks = rest % KS, ct = rest / KS;
    int k = ks * 32 + ((lane >> 4) << 3) + j;
    int c = ct * 16 + (lane & 15);
    P[idx] = (_Float16)W[k * N + c];
}

// ---- MFMA irrep_linear: 16 nodes/block, 4 waves (wave w: mat w = s,vx,vy,vz). In-place safe.
__global__ __launch_bounds__(256) void k_irrep_m(
    const float* __restrict__ X, const _Float16* __restrict__ pW0,
    const float* __restrict__ b0, const _Float16* __restrict__ pW1,
    float* __restrict__ out) {
    __shared__ _Float16 Xr[4][16][136];   // [mat][node][k], +8 pad
    const int t = threadIdx.x, lane = t & 63, w = t >> 6;
    const int nb = blockIdx.x * 16;
    for (int idx = t; idx < 16 * 128; idx += 256) {
        int n = idx >> 7, c4 = idx & 127;
        const float4 v = *(const float4*)(X + (size_t)(nb + n) * 512 + 4 * c4);
        float vals[4] = {v.x, v.y, v.z, v.w};
        int c = 4 * c4;
#pragma unroll
        for (int j = 0; j < 4; ++j) {
            int cc = c + j;
            if (cc < 128) Xr[0][n][cc] = (_Float16)vals[j];
            else { int d = cc - 128; Xr[1 + d % 3][n][d / 3] = (_Float16)vals[j]; }
        }
    }
    __syncthreads();
    const _Float16* pW = (w == 0) ? pW0 : pW1;
    const int row16 = lane & 15, kg = lane >> 4;
    f32x4 acc[8];
    const f32x4 zero = {0.0f, 0.0f, 0.0f, 0.0f};
#pragma unroll
    for (int ct = 0; ct < 8; ++ct) acc[ct] = zero;
    for (int ks = 0; ks < 4; ++ks) {
        const half8 a = *(const half8*)&Xr[w][row16][ks * 32 + kg * 8];
#pragma unroll
        for (int ct = 0; ct < 8; ++ct) {
            const half8 b = *(const half8*)(pW + (((ct * 4 + ks) * 64 + lane) << 3));
            acc[ct] = __builtin_amdgcn_mfma_f32_16x16x32_f16(a, b, acc[ct], 0, 0, 0);
        }
    }
#pragma unroll
    for (int ct = 0; ct < 8; ++ct) {
        const int col = ct * 16 + row16;
        const float bb = (w == 0) ? b0[col] : 0.0f;
#pragma unroll
        for (int r = 0; r < 4; ++r) {
            const int node = nb + kg * 4 + r;
            const float val = acc[ct][r] * RS128 + bb;
            if (w == 0) out[(size_t)node * 512 + col] = val;
            else out[(size_t)node * 512 + 128 + 3 * col + (w - 1)] = val;
        }
    }
}

// ---- MFMA fused norm_gate + irrep_linear(Wn) ----
__global__ __launch_bounds__(256) void k_self_m(
    const float* __restrict__ X,
    const _Float16* __restrict__ png1, const float* __restrict__ ngb1,
    const _Float16* __restrict__ png2, const float* __restrict__ ngb2,
    const _Float16* __restrict__ pWn0, const float* __restrict__ bn0,
    const _Float16* __restrict__ pWn1,
    float* __restrict__ selfx) {
    __shared__ _Float16 f0h[16][264];     // f0, later g
    __shared__ _Float16 t1h[16][264];
    __shared__ _Float16 xvh[3][16][136];
    const int t = threadIdx.x, lane = t & 63, w = t >> 6;
    const int nb = blockIdx.x * 16;
    const int row16 = lane & 15, kg = lane >> 4;
    const f32x4 zero = {0.0f, 0.0f, 0.0f, 0.0f};

    for (int idx = t; idx < 16 * 128; idx += 256) {
        int n = idx >> 7, c4 = idx & 127;
        const float4 v = *(const float4*)(X + (size_t)(nb + n) * 512 + 4 * c4);
        float vals[4] = {v.x, v.y, v.z, v.w};
        int c = 4 * c4;
#pragma unroll
        for (int j = 0; j < 4; ++j) {
            int cc = c + j;
            if (cc < 128) f0h[n][cc] = (_Float16)vals[j];
            else { int d = cc - 128; xvh[d % 3][n][d / 3] = (_Float16)vals[j]; }
        }
    }
    __syncthreads();
    for (int idx = t; idx < 16 * 128; idx += 256) {
        int n = idx >> 7, u = idx & 127;
        float a = (float)xvh[0][n][u], b = (float)xvh[1][n][u], c = (float)xvh[2][n][u];
        f0h[n][128 + u] = (_Float16)sqrtf(fmaf(a, a, fmaf(b, b, fmaf(c, c, 1e-12f))));
    }
    __syncthreads();
    // MLP1: t1 = silu(f0 @ ngW1 + b1); wave w owns cols 64w..64w+63
    {
        f32x4 acc[4];
#pragma unroll
        for (int i = 0; i < 4; ++i) acc[i] = zero;
        for (int ks = 0; ks < 8; ++ks) {
            const half8 a = *(const half8*)&f0h[row16][ks * 32 + kg * 8];
#pragma unroll
            for (int c2 = 0; c2 < 4; ++c2) {
                const int ct = 4 * w + c2;
                const half8 b = *(const half8*)(png1 + (((ct * 8 + ks) * 64 + lane) << 3));
                acc[c2] = __builtin_amdgcn_mfma_f32_16x16x32_f16(a, b, acc[c2], 0, 0, 0);
            }
        }
#pragma unroll
        for (int c2 = 0; c2 < 4; ++c2) {
            const int col = (4 * w + c2) * 16 + row16;
            const float bb = ngb1[col];
#pragma unroll
            for (int r = 0; r < 4; ++r) {
                const float z = acc[c2][r] + bb;
                t1h[kg * 4 + r][col] = (_Float16)(z / (1.0f + __expf(-z)));
            }
        }
    }
    __syncthreads();
    // MLP2: g = t1 @ ngW2 + b2 -> f0h
    {
        f32x4 acc[4];
#pragma unroll
        for (int i = 0; i < 4; ++i) acc[i] = zero;
        for (int ks = 0; ks < 8; ++ks) {
            const half8 a = *(const half8*)&t1h[row16][ks * 32 + kg * 8];
#pragma unroll
            for (int c2 = 0; c2 < 4; ++c2) {
                const int ct = 4 * w + c2;
                const half8 b = *(const half8*)(png2 + (((ct * 8 + ks) * 64 + lane) << 3));
                acc[c2] = __builtin_amdgcn_mfma_f32_16x16x32_f16(a, b, acc[c2], 0, 0, 0);
            }
        }
        __syncthreads();   // f0h reads (MLP1 A) done; safe to overwrite
#pragma unroll
        for (int c2 = 0; c2 < 4; ++c2) {
            const int col = (4 * w + c2) * 16 + row16;
            const float bb = ngb2[col];
#pragma unroll
            for (int r = 0; r < 4; ++r)
                f0h[kg * 4 + r][col] = (_Float16)(acc[c2][r] + bb);
        }
    }
    __syncthreads();
    // gate vectors
    for (int idx = t; idx < 16 * 128; idx += 256) {
        int n = idx >> 7, u = idx & 127;
        const _Float16 g = f0h[n][128 + u];
        xvh[0][n][u] = xvh[0][n][u] * g;
        xvh[1][n][u] = xvh[1][n][u] * g;
        xvh[2][n][u] = xvh[2][n][u] * g;
    }
    __syncthreads();
    // final irrep with Wn: wave w -> mat w
    {
        const _Float16* pw = (w == 0) ? pWn0 : pWn1;
        f32x4 acc[8];
#pragma unroll
        for (int ct = 0; ct < 8; ++ct) acc[ct] = zero;
        for (int ks = 0; ks < 4; ++ks) {
            const half8 a = (w == 0)
                ? *(const half8*)&f0h[row16][ks * 32 + kg * 8]
                : *(const half8*)&xvh[w - 1][row16][ks * 32 + kg * 8];
#pragma unroll
            for (int ct = 0; ct < 8; ++ct) {
                const half8 b = *(const half8*)(pw + (((ct * 4 + ks) * 64 + lane) << 3));
                acc[ct] = __builtin_amdgcn_mfma_f32_16x16x32_f16(a, b, acc[ct], 0, 0, 0);
            }
        }
#pragma unroll
        for (int ct = 0; ct < 8; ++ct) {
            const int col = ct * 16 + row16;
            const float bb = (w == 0) ? bn0[col] : 0.0f;
#pragma unroll
            for (int r = 0; r < 4; ++r) {
                const int node = nb + kg * 4 + r;
                const float val = acc[ct][r] * RS128 + bb;
                if (w == 0) selfx[(size_t)node * 512 + col] = val;
                else selfx[(size_t)node * 512 + 128 + 3 * col + (w - 1)] = val;
            }
        }
    }
}

// per-node halves of MLP1: pAB[n][0:32] = s_n @ l0W1[0:128], pAB[n][32:64] = s_n @ l0W1[128:256]
__global__ __launch_bounds__(256) void k_pre(
    const float* __restrict__ prex, const float* __restrict__ l0W1,
    float* __restrict__ pAB) {
    __shared__ float xs[8][128];
    const int t = threadIdx.x;
    const int nb = blockIdx.x * 8;
    for (int idx = t; idx < 8 * 128; idx += 256) {
        int n = idx >> 7, u = idx & 127;
        xs[n][u] = prex[(size_t)(nb + n) * 512 + u];
    }
    __syncthreads();
    const int n = t >> 5, k = t & 31;
    float a = 0, b = 0;
    for (int u = 0; u < 128; ++u) {
        float s = xs[n][u];
        a = fmaf(s, l0W1[u * 32 + k], a);
        b = fmaf(s, l0W1[(128 + u) * 32 + k], b);
    }
    pAB[(size_t)(nb + n) * 64 + k] = a;
    pAB[(size_t)(nb + n) * 64 + 32 + k] = b;
}

// convert+transpose edge-MLP2 weights to fp16: W_t[col][k] = W[k*512+col]
__global__ __launch_bounds__(256) void k_wconv(
    const float* __restrict__ fcnW2, const float* __restrict__ l0W2,
    _Float16* __restrict__ Wf_t, _Float16* __restrict__ Wl_t) {
    int idx = blockIdx.x * 256 + threadIdx.x;   // 16384
    int k = idx & 31, c = idx >> 5;
    Wf_t[c * 32 + k] = (_Float16)fcnW2[k * 512 + c];
    Wl_t[c * 32 + k] = (_Float16)l0W2[k * 512 + c];
}

// ---- CSR build ----
__global__ __launch_bounds__(256) void k_deg(const int* __restrict__ ei, int* __restrict__ deg) {
    int e = blockIdx.x * 256 + threadIdx.x;
    if (e < EE) atomicAdd(&deg[ei[e]], 1);
}

__global__ __launch_bounds__(1024) void k_scan(const int* __restrict__ deg, int* __restrict__ row_ptr) {
    __shared__ int part[1024];
    const int t = threadIdx.x;
    const int base = t * 10;
    int loc[10];
    int s = 0;
#pragma unroll
    for (int i = 0; i < 10; ++i) {
        int idx = base + i;
        int d = (idx < NN) ? deg[idx] : 0;
        loc[i] = s;
        s += d;
    }
    part[t] = s;
    __syncthreads();
    for (int off = 1; off < 1024; off <<= 1) {
        int v = (t >= off) ? part[t - off] : 0;
        __syncthreads();
        part[t] += v;
        __syncthreads();
    }
    int excl = (t > 0) ? part[t - 1] : 0;
#pragma unroll
    for (int i = 0; i < 10; ++i) {
        int idx = base + i;
        if (idx <= NN) row_ptr[idx] = excl + loc[i];
    }
}

__global__ __launch_bounds__(256) void k_fill(const int* __restrict__ ei,
                                              const int* __restrict__ row_ptr,
                                              int* __restrict__ cursor,
                                              int* __restrict__ csr_eid) {
    int e = blockIdx.x * 256 + threadIdx.x;
    if (e < EE) {
        int d = ei[e];
        int pos = atomicAdd(&cursor[d], 1);
        csr_eid[row_ptr[d] + pos] = e;
    }
}

// ---- MFMA hidden units, CSR-position order: hh[p][0:32]=h1, hh[p][32:64]=ha (fp16) ----
// 32 csr positions/block, 4 waves: wave w -> (mtile = w>>1, coltile = w&1)
__global__ __launch_bounds__(256) void k_hidden_m(
    const float* __restrict__ prex, const float* __restrict__ pAB,
    const int* __restrict__ edge_index, const float* __restrict__ edge_attr,
    const int* __restrict__ csr_eid,
    const _Float16* __restrict__ pWc,   // packed l0W1[256:384][32]  (K=128,N=32)
    const _Float16* __restrict__ pWa,   // packed fcnW1              (K=32, N=32)
    __half* __restrict__ hh) {
    const int pb = blockIdx.x * 32;
    const int t = threadIdx.x, lane = t & 63, w = t >> 6;
    __shared__ _Float16 ipl[32][132];
    __shared__ _Float16 eal[32][36];
    __shared__ _Float16 h1o[32][32];
    __shared__ _Float16 hao[32][32];
    __shared__ int dsts[32], srcs[32], eids[32];

    if (t < 32) {
        const int id = csr_eid[pb + t];
        eids[t] = id;
        dsts[t] = edge_index[id];
        srcs[t] = edge_index[EE + id];
    }
    __syncthreads();
    for (int idx = t; idx < 32 * 32; idx += 256) {
        int e = idx >> 5, j = idx & 31;
        eal[e][j] = (_Float16)edge_attr[(size_t)eids[e] * 32 + j];
    }
    for (int idx = t; idx < 32 * 128; idx += 256) {
        int e = idx >> 7, u = idx & 127;
        const float* pd = prex + (size_t)dsts[e] * 512 + 128 + 3 * u;
        const float* ps = prex + (size_t)srcs[e] * 512 + 128 + 3 * u;
        ipl[e][u] = (_Float16)((pd[0] * ps[0] + pd[1] * ps[1] + pd[2] * ps[2]) * R3);
    }
    __syncthreads();

    const int row16 = lane & 15, kg = lane >> 4;
    const int mt = w >> 1, ct = w & 1;
    const int e0 = mt * 16;
    const f32x4 zero = {0.0f, 0.0f, 0.0f, 0.0f};
    const int kc = ct * 16 + row16;

    // h1 = ssp((pA[dst] + pB[src] + ip@Wc) * RS384)
    {
        f32x4 acc = zero;
#pragma unroll
        for (int ks = 0; ks < 4; ++ks) {
            const half8 a = *(const half8*)&ipl[e0 + row16][ks * 32 + kg * 8];
            const half8 b = *(const half8*)(pWc + (((ct * 4 + ks) * 64 + lane) << 3));
            acc = __builtin_amdgcn_mfma_f32_16x16x32_f16(a, b, acc, 0, 0, 0);
        }
#pragma unroll
        for (int r = 0; r < 4; ++r) {
            const int e = e0 + kg * 4 + r;
            const float v = acc[r] + pAB[(size_t)dsts[e] * 64 + kc]
                                   + pAB[(size_t)srcs[e] * 64 + 32 + kc];
            h1o[e][kc] = (_Float16)sspf(v * RS384);
        }
    }
    // ha = ssp((ea @ fcnW1) * RS32)
    {
        const half8 a = *(const half8*)&eal[e0 + row16][kg * 8];
        const half8 b = *(const half8*)(pWa + ((ct * 64 + lane) << 3));
        f32x4 acc = __builtin_amdgcn_mfma_f32_16x16x32_f16(a, b, zero, 0, 0, 0);
#pragma unroll
        for (int r = 0; r < 4; ++r) {
            const int e = e0 + kg * 4 + r;
            hao[e][kc] = (_Float16)sspf((float)acc[r] * RS32);
        }
    }
    __syncthreads();
    // coalesced store: hh[pb+e][64] as 32 u32 per edge
    for (int idx = t; idx < 32 * 32; idx += 256) {
        const int e = idx >> 5, j = idx & 31;
        unsigned vv;
        if (j < 16) {
            __half2 h2 = __halves2half2((__half)h1o[e][2 * j], (__half)h1o[e][2 * j + 1]);
            vv = *(unsigned*)&h2;
        } else {
            const int jj = j - 16;
            __half2 h2 = __halves2half2((__half)hao[e][2 * jj], (__half)hao[e][2 * jj + 1]);
            vv = *(unsigned*)&h2;
        }
        ((unsigned*)hh)[(size_t)(pb + e) * 32 + j] = vv;
    }
}

// ---- per-dst accumulate via MFMA (hh is CSR-position-ordered -> contiguous stage) ----
__global__ __launch_bounds__(512) void k_accum(
    const __half* __restrict__ hh, const float* __restrict__ selfx,
    const int* __restrict__ edge_index, const float* __restrict__ edge_sh,
    const int* __restrict__ row_ptr, const int* __restrict__ csr_eid,
    const _Float16* __restrict__ Wf_t, const _Float16* __restrict__ Wl_t,
    float* __restrict__ outacc) {
    const int dst = blockIdx.x;
    const int t = threadIdx.x;
    const int lane = t & 63;
    const int wid = t >> 6;          // 0..7
    const int beg = row_ptr[dst];
    const int ne = row_ptr[dst + 1] - beg;

    __shared__ __align__(16) _Float16 h1s[4][16][8];   // [kc][edge][j], k = kc*8+j
    __shared__ __align__(16) _Float16 has[4][16][8];
    __shared__ float shl[16][4];
    __shared__ int srcs[16];

    const int lcol = lane & 15;
    const int kg = lane >> 4;        // 0..3
    const int u = 16 * wid + lcol;   // 0..127
    const int koff = kg * 8;

    half8 bf[4], bl[4];
#pragma unroll
    for (int q = 0; q < 4; ++q) {
        const int col = q * 128 + u;
        bf[q] = *(const half8*)(Wf_t + col * 32 + koff);
        bl[q] = *(const half8*)(Wl_t + col * 32 + koff);
    }

    float acc0 = 0, acc1 = 0, acc2 = 0, acc3 = 0;
    const float inv32 = 1.0f / 32.0f;

    for (int c0 = 0; c0 < ne; c0 += 16) {
        const int ce = min(16, ne - c0);
        __syncthreads();
        if (t < 16) {
            const int id = csr_eid[beg + c0 + ((t < ce) ? t : 0)];
            srcs[t] = (t < ce) ? edge_index[EE + id] : 0;
            const float4 s = *(const float4*)(edge_sh + (size_t)id * 4);
            shl[t][0] = s.x; shl[t][1] = s.y; shl[t][2] = s.z; shl[t][3] = s.w;
        }
        {
            const int e = t >> 5, w = t & 31;
            const unsigned val = (e < ce)
                ? ((const unsigned*)hh)[(size_t)(beg + c0 + e) * 32 + w] : 0u;
            if (w < 16) ((unsigned*)h1s)[(w >> 2) * 64 + e * 4 + (w & 3)] = val;
            else        ((unsigned*)has)[((w - 16) >> 2) * 64 + e * 4 + ((w - 16) & 3)] = val;
        }
        __syncthreads();

        const half8 haf = *(const half8*)(&has[kg][lcol][0]);
        const half8 h1f = *(const half8*)(&h1s[kg][lcol][0]);
        const f32x4 zero = {0.0f, 0.0f, 0.0f, 0.0f};
        f32x4 A[4], B[4];
#pragma unroll
        for (int q = 0; q < 4; ++q) {
            A[q] = __builtin_amdgcn_mfma_f32_16x16x32_f16(haf, bf[q], zero, 0, 0, 0);
            B[q] = __builtin_amdgcn_mfma_f32_16x16x32_f16(h1f, bl[q], zero, 0, 0, 0);
        }
#pragma unroll
        for (int r = 0; r < 4; ++r) {
            const int e = kg * 4 + r;
            const float w1 = A[0][r] * B[0][r] * inv32;
            const float w2 = A[1][r] * B[1][r] * inv32;
            const float w3 = A[2][r] * B[2][r] * inv32;
            const float w4 = A[3][r] * B[3][r] * inv32;
            const int src = srcs[e];
            const float sh0 = shl[e][0], s1x = shl[e][1], s1y = shl[e][2], s1z = shl[e][3];
            const float* sr = selfx + (size_t)src * 512;
            const float xs0 = sr[u];
            const float* sv = sr + 128 + 3 * u;
            const float xv0 = sv[0], xv1 = sv[1], xv2 = sv[2];
            const float dv = xv0 * s1x + xv1 * s1y + xv2 * s1z;
            acc0 += 0.5f * (w1 * xs0 * sh0 + w4 * dv * R3);
            acc1 += C1V * (w2 * xs0 * s1x + w3 * xv0 * sh0);
            acc2 += C1V * (w2 * xs0 * s1y + w3 * xv1 * sh0);
            acc3 += C1V * (w2 * xs0 * s1z + w3 * xv2 * sh0);
        }
    }

    acc0 += __shfl_xor(acc0, 16, 64); acc0 += __shfl_xor(acc0, 32, 64);
    acc1 += __shfl_xor(acc1, 16, 64); acc1 += __shfl_xor(acc1, 32, 64);
    acc2 += __shfl_xor(acc2, 16, 64); acc2 += __shfl_xor(acc2, 32, 64);
    acc3 += __shfl_xor(acc3, 16, 64); acc3 += __shfl_xor(acc3, 32, 64);

    if (lane < 16) {
        const size_t g = (size_t)dst * 512;
        outacc[g + u] = acc0 + selfx[g + u];
        outacc[g + 128 + 3 * u + 0] = acc1 + selfx[g + 128 + 3 * u + 0];
        outacc[g + 128 + 3 * u + 1] = acc2 + selfx[g + 128 + 3 * u + 1];
        outacc[g + 128 + 3 * u + 2] = acc3 + selfx[g + 128 + 3 * u + 2];
    }
}

extern "C" void kernel_launch(void* const* d_in, const int* in_sizes, int n_in,
                              void* d_out, int out_size, void* d_ws, size_t ws_size,
                              hipStream_t stream) {
    const float* x = (const float*)d_in[0];
    const int* edge_index = (const int*)d_in[1];
    const float* edge_attr = (const float*)d_in[2];
    const float* edge_sh = (const float*)d_in[3];
    const float* Wp0 = (const float*)d_in[4];
    const float* bp0 = (const float*)d_in[5];
    const float* Wp1 = (const float*)d_in[6];
    const float* ngW1 = (const float*)d_in[7];
    const float* ngb1 = (const float*)d_in[8];
    const float* ngW2 = (const float*)d_in[9];
    const float* ngb2 = (const float*)d_in[10];
    const float* Wn0 = (const float*)d_in[11];
    const float* bn0 = (const float*)d_in[12];
    const float* Wn1 = (const float*)d_in[13];
    const float* fcnW1 = (const float*)d_in[14];
    const float* fcnW2 = (const float*)d_in[15];
    const float* l0W1 = (const float*)d_in[16];
    const float* l0W2 = (const float*)d_in[17];
    const float* Wo0 = (const float*)d_in[18];
    const float* bo0 = (const float*)d_in[19];
    const float* Wo1 = (const float*)d_in[20];

    float* out = (float*)d_out;
    float* prex = out;                       // d_out as pre_x scratch; k_accum overwrites it
    float* selfx = (float*)d_ws;
    int* deg = (int*)(selfx + (size_t)NN * 512);
    int* cursor = deg + NN;
    int* row_ptr = cursor + NN;
    int* csr_eid = row_ptr + NN + 1;
    float* pAB = (float*)(csr_eid + EE);
    __half* hh = (__half*)(pAB + (size_t)NN * 64);
    _Float16* Wf_t = (_Float16*)(hh + (size_t)EE * 64);
    _Float16* Wl_t = Wf_t + 512 * 32;
    _Float16* pWp0 = Wl_t + 512 * 32;
    _Float16* pWp1 = pWp0 + 128 * 128;
    _Float16* pWn0 = pWp1 + 128 * 128;
    _Float16* pWn1 = pWn0 + 128 * 128;
    _Float16* pWo0 = pWn1 + 128 * 128;
    _Float16* pWo1 = pWo0 + 128 * 128;
    _Float16* png1 = pWo1 + 128 * 128;
    _Float16* png2 = png1 + 256 * 256;
    _Float16* pWc  = png2 + 256 * 256;
    _Float16* pWa  = pWc + 128 * 32;

    hipMemsetAsync(deg, 0, 2 * NN * sizeof(int), stream);  // deg + cursor

    k_pack<<<64, 256, 0, stream>>>(Wp0, pWp0, 128, 128);
    k_pack<<<64, 256, 0, stream>>>(Wp1, pWp1, 128, 128);
    k_pack<<<64, 256, 0, stream>>>(Wn0, pWn0, 128, 128);
    k_pack<<<64, 256, 0, stream>>>(Wn1, pWn1, 128, 128);
    k_pack<<<64, 256, 0, stream>>>(Wo0, pWo0, 128, 128);
    k_pack<<<64, 256, 0, stream>>>(Wo1, pWo1, 128, 128);
    k_pack<<<256, 256, 0, stream>>>(ngW1, png1, 256, 256);
    k_pack<<<256, 256, 0, stream>>>(ngW2, png2, 256, 256);
    k_pack<<<16, 256, 0, stream>>>(l0W1 + 256 * 32, pWc, 128, 32);
    k_pack<<<4, 256, 0, stream>>>(fcnW1, pWa, 32, 32);
    k_wconv<<<64, 256, 0, stream>>>(fcnW2, l0W2, Wf_t, Wl_t);

    k_irrep_m<<<NN / 16, 256, 0, stream>>>(x, pWp0, bp0, pWp1, prex);
    k_pre<<<NN / 8, 256, 0, stream>>>(prex, l0W1, pAB);
    k_self_m<<<NN / 16, 256, 0, stream>>>(x, png1, ngb1, png2, ngb2, pWn0, bn0, pWn1, selfx);
    k_deg<<<EE / 256, 256, 0, stream>>>(edge_index, deg);
    k_scan<<<1, 1024, 0, stream>>>(deg, row_ptr);
    k_fill<<<EE / 256, 256, 0, stream>>>(edge_index, row_ptr, cursor, csr_eid);
    k_hidden_m<<<EE / 32, 256, 0, stream>>>(prex, pAB, edge_index, edge_attr, csr_eid,
                                            pWc, pWa, hh);
    k_accum<<<NN, 512, 0, stream>>>(hh, selfx, edge_index, edge_sh, row_ptr, csr_eid,
                                    Wf_t, Wl_t, out);
    k_irrep_m<<<NN / 16, 256, 0, stream>>>(out, pWo0, bo0, pWo1, out);
}

// Round 10
// 282.599 us; speedup vs baseline: 4.6748x; 1.0410x over previous
//
#include <hip/hip_runtime.h>
#include <hip/hip_fp16.h>
#include <math.h>

#define NN 10000
#define EE 160000

#define RS128 0.08838834764831845f   // 1/sqrt(128)
#define RS384 0.05103103630798287f   // 1/sqrt(384)
#define RS32  0.17677669529663687f   // 1/sqrt(32)
#define R3    0.57735026918962576f   // 1/sqrt(3)
#define C1V   0.86602540378443865f   // sqrt(3)/2

typedef _Float16 half8 __attribute__((ext_vector_type(8)));
typedef float f32x4 __attribute__((ext_vector_type(4)));

__device__ __forceinline__ float sspf(float x) {
    return fmaxf(x, 0.0f) + log1pf(__expf(-fabsf(x))) - 0.69314718055994530942f;
}

// ---- pack W[K][N] fp32 -> fragment-ordered fp16: P[((ct*KS+ks)*64+lane)*8+j] = W[k][c]
__global__ __launch_bounds__(256) void k_pack(
    const float* __restrict__ W, _Float16* __restrict__ P, int K, int N) {
    int idx = blockIdx.x * 256 + threadIdx.x;
    if (idx >= K * N) return;
    const int KS = K >> 5;
    int j = idx & 7, lane = (idx >> 3) & 63, rest = idx >> 9;
    int ks = rest % KS, ct = rest / KS;
    int k = ks * 32 + ((lane >> 4) << 3) + j;
    int c = ct * 16 + (lane & 15);
    P[idx] = (_Float16)W[k * N + c];
}

// ---- MFMA irrep_linear: 16 nodes/block, 4 waves. In-place safe.
__global__ __launch_bounds__(256) void k_irrep_m(
    const float* __restrict__ X, const _Float16* __restrict__ pW0,
    const float* __restrict__ b0, const _Float16* __restrict__ pW1,
    float* __restrict__ out) {
    __shared__ _Float16 Xr[4][16][136];
    const int t = threadIdx.x, lane = t & 63, w = t >> 6;
    const int nb = blockIdx.x * 16;
    for (int idx = t; idx < 16 * 128; idx += 256) {
        int n = idx >> 7, c4 = idx & 127;
        const float4 v = *(const float4*)(X + (size_t)(nb + n) * 512 + 4 * c4);
        float vals[4] = {v.x, v.y, v.z, v.w};
        int c = 4 * c4;
#pragma unroll
        for (int j = 0; j < 4; ++j) {
            int cc = c + j;
            if (cc < 128) Xr[0][n][cc] = (_Float16)vals[j];
            else { int d = cc - 128; Xr[1 + d % 3][n][d / 3] = (_Float16)vals[j]; }
        }
    }
    __syncthreads();
    const _Float16* pW = (w == 0) ? pW0 : pW1;
    const int row16 = lane & 15, kg = lane >> 4;
    f32x4 acc[8];
    const f32x4 zero = {0.0f, 0.0f, 0.0f, 0.0f};
#pragma unroll
    for (int ct = 0; ct < 8; ++ct) acc[ct] = zero;
    for (int ks = 0; ks < 4; ++ks) {
        const half8 a = *(const half8*)&Xr[w][row16][ks * 32 + kg * 8];
#pragma unroll
        for (int ct = 0; ct < 8; ++ct) {
            const half8 b = *(const half8*)(pW + (((ct * 4 + ks) * 64 + lane) << 3));
            acc[ct] = __builtin_amdgcn_mfma_f32_16x16x32_f16(a, b, acc[ct], 0, 0, 0);
        }
    }
#pragma unroll
    for (int ct = 0; ct < 8; ++ct) {
        const int col = ct * 16 + row16;
        const float bb = (w == 0) ? b0[col] : 0.0f;
#pragma unroll
        for (int r = 0; r < 4; ++r) {
            const int node = nb + kg * 4 + r;
            const float val = acc[ct][r] * RS128 + bb;
            if (w == 0) out[(size_t)node * 512 + col] = val;
            else out[(size_t)node * 512 + 128 + 3 * col + (w - 1)] = val;
        }
    }
}

// ---- MFMA fused norm_gate + irrep_linear(Wn) ----
__global__ __launch_bounds__(256) void k_self_m(
    const float* __restrict__ X,
    const _Float16* __restrict__ png1, const float* __restrict__ ngb1,
    const _Float16* __restrict__ png2, const float* __restrict__ ngb2,
    const _Float16* __restrict__ pWn0, const float* __restrict__ bn0,
    const _Float16* __restrict__ pWn1,
    float* __restrict__ selfx) {
    __shared__ _Float16 f0h[16][264];
    __shared__ _Float16 t1h[16][264];
    __shared__ _Float16 xvh[3][16][136];
    const int t = threadIdx.x, lane = t & 63, w = t >> 6;
    const int nb = blockIdx.x * 16;
    const int row16 = lane & 15, kg = lane >> 4;
    const f32x4 zero = {0.0f, 0.0f, 0.0f, 0.0f};

    for (int idx = t; idx < 16 * 128; idx += 256) {
        int n = idx >> 7, c4 = idx & 127;
        const float4 v = *(const float4*)(X + (size_t)(nb + n) * 512 + 4 * c4);
        float vals[4] = {v.x, v.y, v.z, v.w};
        int c = 4 * c4;
#pragma unroll
        for (int j = 0; j < 4; ++j) {
            int cc = c + j;
            if (cc < 128) f0h[n][cc] = (_Float16)vals[j];
            else { int d = cc - 128; xvh[d % 3][n][d / 3] = (_Float16)vals[j]; }
        }
    }
    __syncthreads();
    for (int idx = t; idx < 16 * 128; idx += 256) {
        int n = idx >> 7, u = idx & 127;
        float a = (float)xvh[0][n][u], b = (float)xvh[1][n][u], c = (float)xvh[2][n][u];
        f0h[n][128 + u] = (_Float16)sqrtf(fmaf(a, a, fmaf(b, b, fmaf(c, c, 1e-12f))));
    }
    __syncthreads();
    {
        f32x4 acc[4];
#pragma unroll
        for (int i = 0; i < 4; ++i) acc[i] = zero;
        for (int ks = 0; ks < 8; ++ks) {
            const half8 a = *(const half8*)&f0h[row16][ks * 32 + kg * 8];
#pragma unroll
            for (int c2 = 0; c2 < 4; ++c2) {
                const int ct = 4 * w + c2;
                const half8 b = *(const half8*)(png1 + (((ct * 8 + ks) * 64 + lane) << 3));
                acc[c2] = __builtin_amdgcn_mfma_f32_16x16x32_f16(a, b, acc[c2], 0, 0, 0);
            }
        }
#pragma unroll
        for (int c2 = 0; c2 < 4; ++c2) {
            const int col = (4 * w + c2) * 16 + row16;
            const float bb = ngb1[col];
#pragma unroll
            for (int r = 0; r < 4; ++r) {
                const float z = acc[c2][r] + bb;
                t1h[kg * 4 + r][col] = (_Float16)(z / (1.0f + __expf(-z)));
            }
        }
    }
    __syncthreads();
    {
        f32x4 acc[4];
#pragma unroll
        for (int i = 0; i < 4; ++i) acc[i] = zero;
        for (int ks = 0; ks < 8; ++ks) {
            const half8 a = *(const half8*)&t1h[row16][ks * 32 + kg * 8];
#pragma unroll
            for (int c2 = 0; c2 < 4; ++c2) {
                const int ct = 4 * w + c2;
                const half8 b = *(const half8*)(png2 + (((ct * 8 + ks) * 64 + lane) << 3));
                acc[c2] = __builtin_amdgcn_mfma_f32_16x16x32_f16(a, b, acc[c2], 0, 0, 0);
            }
        }
        __syncthreads();
#pragma unroll
        for (int c2 = 0; c2 < 4; ++c2) {
            const int col = (4 * w + c2) * 16 + row16;
            const float bb = ngb2[col];
#pragma unroll
            for (int r = 0; r < 4; ++r)
                f0h[kg * 4 + r][col] = (_Float16)(acc[c2][r] + bb);
        }
    }
    __syncthreads();
    for (int idx = t; idx < 16 * 128; idx += 256) {
        int n = idx >> 7, u = idx & 127;
        const _Float16 g = f0h[n][128 + u];
        xvh[0][n][u] = xvh[0][n][u] * g;
        xvh[1][n][u] = xvh[1][n][u] * g;
        xvh[2][n][u] = xvh[2][n][u] * g;
    }
    __syncthreads();
    {
        const _Float16* pw = (w == 0) ? pWn0 : pWn1;
        f32x4 acc[8];
#pragma unroll
        for (int ct = 0; ct < 8; ++ct) acc[ct] = zero;
        for (int ks = 0; ks < 4; ++ks) {
            const half8 a = (w == 0)
                ? *(const half8*)&f0h[row16][ks * 32 + kg * 8]
                : *(const half8*)&xvh[w - 1][row16][ks * 32 + kg * 8];
#pragma unroll
            for (int ct = 0; ct < 8; ++ct) {
                const half8 b = *(const half8*)(pw + (((ct * 4 + ks) * 64 + lane) << 3));
                acc[ct] = __builtin_amdgcn_mfma_f32_16x16x32_f16(a, b, acc[ct], 0, 0, 0);
            }
        }
#pragma unroll
        for (int ct = 0; ct < 8; ++ct) {
            const int col = ct * 16 + row16;
            const float bb = (w == 0) ? bn0[col] : 0.0f;
#pragma unroll
            for (int r = 0; r < 4; ++r) {
                const int node = nb + kg * 4 + r;
                const float val = acc[ct][r] * RS128 + bb;
                if (w == 0) selfx[(size_t)node * 512 + col] = val;
                else selfx[(size_t)node * 512 + 128 + 3 * col + (w - 1)] = val;
            }
        }
    }
}

// per-node halves of MLP1
__global__ __launch_bounds__(256) void k_pre(
    const float* __restrict__ prex, const float* __restrict__ l0W1,
    float* __restrict__ pAB) {
    __shared__ float xs[8][128];
    const int t = threadIdx.x;
    const int nb = blockIdx.x * 8;
    for (int idx = t; idx < 8 * 128; idx += 256) {
        int n = idx >> 7, u = idx & 127;
        xs[n][u] = prex[(size_t)(nb + n) * 512 + u];
    }
    __syncthreads();
    const int n = t >> 5, k = t & 31;
    float a = 0, b = 0;
    for (int u = 0; u < 128; ++u) {
        float s = xs[n][u];
        a = fmaf(s, l0W1[u * 32 + k], a);
        b = fmaf(s, l0W1[(128 + u) * 32 + k], b);
    }
    pAB[(size_t)(nb + n) * 64 + k] = a;
    pAB[(size_t)(nb + n) * 64 + 32 + k] = b;
}

// convert+transpose edge-MLP2 weights to fp16
__global__ __launch_bounds__(256) void k_wconv(
    const float* __restrict__ fcnW2, const float* __restrict__ l0W2,
    _Float16* __restrict__ Wf_t, _Float16* __restrict__ Wl_t) {
    int idx = blockIdx.x * 256 + threadIdx.x;
    int k = idx & 31, c = idx >> 5;
    Wf_t[c * 32 + k] = (_Float16)fcnW2[k * 512 + c];
    Wl_t[c * 32 + k] = (_Float16)l0W2[k * 512 + c];
}

// ---- CSR build ----
__global__ __launch_bounds__(256) void k_deg(const int* __restrict__ ei, int* __restrict__ deg) {
    int e = blockIdx.x * 256 + threadIdx.x;
    if (e < EE) atomicAdd(&deg[ei[e]], 1);
}

__global__ __launch_bounds__(1024) void k_scan(const int* __restrict__ deg, int* __restrict__ row_ptr) {
    __shared__ int part[1024];
    const int t = threadIdx.x;
    const int base = t * 10;
    int loc[10];
    int s = 0;
#pragma unroll
    for (int i = 0; i < 10; ++i) {
        int idx = base + i;
        int d = (idx < NN) ? deg[idx] : 0;
        loc[i] = s;
        s += d;
    }
    part[t] = s;
    __syncthreads();
    for (int off = 1; off < 1024; off <<= 1) {
        int v = (t >= off) ? part[t - off] : 0;
        __syncthreads();
        part[t] += v;
        __syncthreads();
    }
    int excl = (t > 0) ? part[t - 1] : 0;
#pragma unroll
    for (int i = 0; i < 10; ++i) {
        int idx = base + i;
        if (idx <= NN) row_ptr[idx] = excl + loc[i];
    }
}

__global__ __launch_bounds__(256) void k_fill(const int* __restrict__ ei,
                                              const int* __restrict__ row_ptr,
                                              int* __restrict__ cursor,
                                              int* __restrict__ csr_eid) {
    int e = blockIdx.x * 256 + threadIdx.x;
    if (e < EE) {
        int d = ei[e];
        int pos = atomicAdd(&cursor[d], 1);
        csr_eid[row_ptr[d] + pos] = e;
    }
}

// ---- MFMA hidden units, CSR-position order ----
__global__ __launch_bounds__(256) void k_hidden_m(
    const float* __restrict__ prex, const float* __restrict__ pAB,
    const int* __restrict__ edge_index, const float* __restrict__ edge_attr,
    const int* __restrict__ csr_eid,
    const _Float16* __restrict__ pWc, const _Float16* __restrict__ pWa,
    __half* __restrict__ hh) {
    const int pb = blockIdx.x * 32;
    const int t = threadIdx.x, lane = t & 63, w = t >> 6;
    __shared__ _Float16 ipl[32][132];
    __shared__ _Float16 eal[32][36];
    __shared__ _Float16 h1o[32][32];
    __shared__ _Float16 hao[32][32];
    __shared__ int dsts[32], srcs[32], eids[32];

    if (t < 32) {
        const int id = csr_eid[pb + t];
        eids[t] = id;
        dsts[t] = edge_index[id];
        srcs[t] = edge_index[EE + id];
    }
    __syncthreads();
    for (int idx = t; idx < 32 * 32; idx += 256) {
        int e = idx >> 5, j = idx & 31;
        eal[e][j] = (_Float16)edge_attr[(size_t)eids[e] * 32 + j];
    }
    for (int idx = t; idx < 32 * 128; idx += 256) {
        int e = idx >> 7, u = idx & 127;
        const float* pd = prex + (size_t)dsts[e] * 512 + 128 + 3 * u;
        const float* ps = prex + (size_t)srcs[e] * 512 + 128 + 3 * u;
        ipl[e][u] = (_Float16)((pd[0] * ps[0] + pd[1] * ps[1] + pd[2] * ps[2]) * R3);
    }
    __syncthreads();

    const int row16 = lane & 15, kg = lane >> 4;
    const int mt = w >> 1, ct = w & 1;
    const int e0 = mt * 16;
    const f32x4 zero = {0.0f, 0.0f, 0.0f, 0.0f};
    const int kc = ct * 16 + row16;

    {
        f32x4 acc = zero;
#pragma unroll
        for (int ks = 0; ks < 4; ++ks) {
            const half8 a = *(const half8*)&ipl[e0 + row16][ks * 32 + kg * 8];
            const half8 b = *(const half8*)(pWc + (((ct * 4 + ks) * 64 + lane) << 3));
            acc = __builtin_amdgcn_mfma_f32_16x16x32_f16(a, b, acc, 0, 0, 0);
        }
#pragma unroll
        for (int r = 0; r < 4; ++r) {
            const int e = e0 + kg * 4 + r;
            const float v = acc[r] + pAB[(size_t)dsts[e] * 64 + kc]
                                   + pAB[(size_t)srcs[e] * 64 + 32 + kc];
            h1o[e][kc] = (_Float16)sspf(v * RS384);
        }
    }
    {
        const half8 a = *(const half8*)&eal[e0 + row16][kg * 8];
        const half8 b = *(const half8*)(pWa + ((ct * 64 + lane) << 3));
        f32x4 acc = __builtin_amdgcn_mfma_f32_16x16x32_f16(a, b, zero, 0, 0, 0);
#pragma unroll
        for (int r = 0; r < 4; ++r) {
            const int e = e0 + kg * 4 + r;
            hao[e][kc] = (_Float16)sspf((float)acc[r] * RS32);
        }
    }
    __syncthreads();
    for (int idx = t; idx < 32 * 32; idx += 256) {
        const int e = idx >> 5, j = idx & 31;
        unsigned vv;
        if (j < 16) {
            __half2 h2 = __halves2half2((__half)h1o[e][2 * j], (__half)h1o[e][2 * j + 1]);
            vv = *(unsigned*)&h2;
        } else {
            const int jj = j - 16;
            __half2 h2 = __halves2half2((__half)hao[e][2 * jj], (__half)hao[e][2 * jj + 1]);
            vv = *(unsigned*)&h2;
        }
        ((unsigned*)hh)[(size_t)(pb + e) * 32 + j] = vv;
    }
}

// ---- per-dst accumulate via MFMA; 4 dsts per block (weight frags amortized) ----
__global__ __launch_bounds__(512) void k_accum(
    const __half* __restrict__ hh, const float* __restrict__ selfx,
    const int* __restrict__ edge_index, const float* __restrict__ edge_sh,
    const int* __restrict__ row_ptr, const int* __restrict__ csr_eid,
    const _Float16* __restrict__ Wf_t, const _Float16* __restrict__ Wl_t,
    float* __restrict__ outacc) {
    const int dst0 = blockIdx.x * 4;
    const int t = threadIdx.x;
    const int lane = t & 63;
    const int wid = t >> 6;          // 0..7

    __shared__ __align__(16) _Float16 h1s[4][16][8];
    __shared__ __align__(16) _Float16 has[4][16][8];
    __shared__ float shl[16][4];
    __shared__ int srcs[16];

    const int lcol = lane & 15;
    const int kg = lane >> 4;
    const int u = 16 * wid + lcol;
    const int koff = kg * 8;

    half8 bf[4], bl[4];
#pragma unroll
    for (int q = 0; q < 4; ++q) {
        const int col = q * 128 + u;
        bf[q] = *(const half8*)(Wf_t + col * 32 + koff);
        bl[q] = *(const half8*)(Wl_t + col * 32 + koff);
    }
    const float inv32 = 1.0f / 32.0f;

    for (int dd = 0; dd < 4; ++dd) {
        const int dst = dst0 + dd;
        const int beg = row_ptr[dst];
        const int ne = row_ptr[dst + 1] - beg;
        float acc0 = 0, acc1 = 0, acc2 = 0, acc3 = 0;

        for (int c0 = 0; c0 < ne; c0 += 16) {
            const int ce = min(16, ne - c0);
            __syncthreads();
            if (t < 16) {
                const int id = csr_eid[beg + c0 + ((t < ce) ? t : 0)];
                srcs[t] = (t < ce) ? edge_index[EE + id] : 0;
                const float4 s = *(const float4*)(edge_sh + (size_t)id * 4);
                shl[t][0] = s.x; shl[t][1] = s.y; shl[t][2] = s.z; shl[t][3] = s.w;
            }
            {
                const int e = t >> 5, w = t & 31;
                const unsigned val = (e < ce)
                    ? ((const unsigned*)hh)[(size_t)(beg + c0 + e) * 32 + w] : 0u;
                if (w < 16) ((unsigned*)h1s)[(w >> 2) * 64 + e * 4 + (w & 3)] = val;
                else        ((unsigned*)has)[((w - 16) >> 2) * 64 + e * 4 + ((w - 16) & 3)] = val;
            }
            __syncthreads();

            const half8 haf = *(const half8*)(&has[kg][lcol][0]);
            const half8 h1f = *(const half8*)(&h1s[kg][lcol][0]);
            const f32x4 zero = {0.0f, 0.0f, 0.0f, 0.0f};
            f32x4 A[4], B[4];
#pragma unroll
            for (int q = 0; q < 4; ++q) {
                A[q] = __builtin_amdgcn_mfma_f32_16x16x32_f16(haf, bf[q], zero, 0, 0, 0);
                B[q] = __builtin_amdgcn_mfma_f32_16x16x32_f16(h1f, bl[q], zero, 0, 0, 0);
            }
#pragma unroll
            for (int r = 0; r < 4; ++r) {
                const int e = kg * 4 + r;
                if (e < ce) {   // predicated: skip dead-slot loads/VALU
                    const float w1 = A[0][r] * B[0][r] * inv32;
                    const float w2 = A[1][r] * B[1][r] * inv32;
                    const float w3 = A[2][r] * B[2][r] * inv32;
                    const float w4 = A[3][r] * B[3][r] * inv32;
                    const int src = srcs[e];
                    const float sh0 = shl[e][0], s1x = shl[e][1], s1y = shl[e][2], s1z = shl[e][3];
                    const float* sr = selfx + (size_t)src * 512;
                    const float xs0 = sr[u];
                    const float* sv = sr + 128 + 3 * u;
                    const float xv0 = sv[0], xv1 = sv[1], xv2 = sv[2];
                    const float dv = xv0 * s1x + xv1 * s1y + xv2 * s1z;
                    acc0 += 0.5f * (w1 * xs0 * sh0 + w4 * dv * R3);
                    acc1 += C1V * (w2 * xs0 * s1x + w3 * xv0 * sh0);
                    acc2 += C1V * (w2 * xs0 * s1y + w3 * xv1 * sh0);
                    acc3 += C1V * (w2 * xs0 * s1z + w3 * xv2 * sh0);
                }
            }
        }

        acc0 += __shfl_xor(acc0, 16, 64); acc0 += __shfl_xor(acc0, 32, 64);
        acc1 += __shfl_xor(acc1, 16, 64); acc1 += __shfl_xor(acc1, 32, 64);
        acc2 += __shfl_xor(acc2, 16, 64); acc2 += __shfl_xor(acc2, 32, 64);
        acc3 += __shfl_xor(acc3, 16, 64); acc3 += __shfl_xor(acc3, 32, 64);

        if (lane < 16) {
            const size_t g = (size_t)dst * 512;
            outacc[g + u] = acc0 + selfx[g + u];
            outacc[g + 128 + 3 * u + 0] = acc1 + selfx[g + 128 + 3 * u + 0];
            outacc[g + 128 + 3 * u + 1] = acc2 + selfx[g + 128 + 3 * u + 1];
            outacc[g + 128 + 3 * u + 2] = acc3 + selfx[g + 128 + 3 * u + 2];
        }
    }
}

extern "C" void kernel_launch(void* const* d_in, const int* in_sizes, int n_in,
                              void* d_out, int out_size, void* d_ws, size_t ws_size,
                              hipStream_t stream) {
    const float* x = (const float*)d_in[0];
    const int* edge_index = (const int*)d_in[1];
    const float* edge_attr = (const float*)d_in[2];
    const float* edge_sh = (const float*)d_in[3];
    const float* Wp0 = (const float*)d_in[4];
    const float* bp0 = (const float*)d_in[5];
    const float* Wp1 = (const float*)d_in[6];
    const float* ngW1 = (const float*)d_in[7];
    const float* ngb1 = (const float*)d_in[8];
    const float* ngW2 = (const float*)d_in[9];
    const float* ngb2 = (const float*)d_in[10];
    const float* Wn0 = (const float*)d_in[11];
    const float* bn0 = (const float*)d_in[12];
    const float* Wn1 = (const float*)d_in[13];
    const float* fcnW1 = (const float*)d_in[14];
    const float* fcnW2 = (const float*)d_in[15];
    const float* l0W1 = (const float*)d_in[16];
    const float* l0W2 = (const float*)d_in[17];
    const float* Wo0 = (const float*)d_in[18];
    const float* bo0 = (const float*)d_in[19];
    const float* Wo1 = (const float*)d_in[20];

    float* out = (float*)d_out;
    float* prex = out;                       // d_out as pre_x scratch; k_accum overwrites it
    float* selfx = (float*)d_ws;
    int* deg = (int*)(selfx + (size_t)NN * 512);
    int* cursor = deg + NN;
    int* row_ptr = cursor + NN;
    int* csr_eid = row_ptr + NN + 1;
    float* pAB = (float*)(csr_eid + EE);
    __half* hh = (__half*)(pAB + (size_t)NN * 64);
    _Float16* Wf_t = (_Float16*)(hh + (size_t)EE * 64);
    _Float16* Wl_t = Wf_t + 512 * 32;
    _Float16* pWp0 = Wl_t + 512 * 32;
    _Float16* pWp1 = pWp0 + 128 * 128;
    _Float16* pWn0 = pWp1 + 128 * 128;
    _Float16* pWn1 = pWn0 + 128 * 128;
    _Float16* pWo0 = pWn1 + 128 * 128;
    _Float16* pWo1 = pWo0 + 128 * 128;
    _Float16* png1 = pWo1 + 128 * 128;
    _Float16* png2 = png1 + 256 * 256;
    _Float16* pWc  = png2 + 256 * 256;
    _Float16* pWa  = pWc + 128 * 32;

    hipMemsetAsync(deg, 0, 2 * NN * sizeof(int), stream);  // deg + cursor

    k_pack<<<64, 256, 0, stream>>>(Wp0, pWp0, 128, 128);
    k_pack<<<64, 256, 0, stream>>>(Wp1, pWp1, 128, 128);
    k_pack<<<64, 256, 0, stream>>>(Wn0, pWn0, 128, 128);
    k_pack<<<64, 256, 0, stream>>>(Wn1, pWn1, 128, 128);
    k_pack<<<64, 256, 0, stream>>>(Wo0, pWo0, 128, 128);
    k_pack<<<64, 256, 0, stream>>>(Wo1, pWo1, 128, 128);
    k_pack<<<256, 256, 0, stream>>>(ngW1, png1, 256, 256);
    k_pack<<<256, 256, 0, stream>>>(ngW2, png2, 256, 256);
    k_pack<<<16, 256, 0, stream>>>(l0W1 + 256 * 32, pWc, 128, 32);
    k_pack<<<4, 256, 0, stream>>>(fcnW1, pWa, 32, 32);
    k_wconv<<<64, 256, 0, stream>>>(fcnW2, l0W2, Wf_t, Wl_t);

    k_irrep_m<<<NN / 16, 256, 0, stream>>>(x, pWp0, bp0, pWp1, prex);
    k_pre<<<NN / 8, 256, 0, stream>>>(prex, l0W1, pAB);
    k_self_m<<<NN / 16, 256, 0, stream>>>(x, png1, ngb1, png2, ngb2, pWn0, bn0, pWn1, selfx);
    k_deg<<<EE / 256, 256, 0, stream>>>(edge_index, deg);
    k_scan<<<1, 1024, 0, stream>>>(deg, row_ptr);
    k_fill<<<EE / 256, 256, 0, stream>>>(edge_index, row_ptr, cursor, csr_eid);
    k_hidden_m<<<EE / 32, 256, 0, stream>>>(prex, pAB, edge_index, edge_attr, csr_eid,
                                            pWc, pWa, hh);
    k_accum<<<NN / 4, 512, 0, stream>>>(hh, selfx, edge_index, edge_sh, row_ptr, csr_eid,
                                        Wf_t, Wl_t, out);
    k_irrep_m<<<NN / 16, 256, 0, stream>>>(out, pWo0, bo0, pWo1, out);
}

// Round 11
// 262.252 us; speedup vs baseline: 5.0375x; 1.0776x over previous
//
#include <hip/hip_runtime.h>
#include <hip/hip_fp16.h>
#include <math.h>

#define NN 10000
#define EE 160000
#define DPB 8   // dsts per k_accum block

#define RS128 0.08838834764831845f   // 1/sqrt(128)
#define RS384 0.05103103630798287f   // 1/sqrt(384)
#define RS32  0.17677669529663687f   // 1/sqrt(32)
#define R3    0.57735026918962576f   // 1/sqrt(3)
#define C1V   0.86602540378443865f   // sqrt(3)/2

typedef _Float16 half8 __attribute__((ext_vector_type(8)));
typedef float f32x4 __attribute__((ext_vector_type(4)));

__device__ __forceinline__ float sspf(float x) {
    return fmaxf(x, 0.0f) + log1pf(__expf(-fabsf(x))) - 0.69314718055994530942f;
}

__device__ __forceinline__ void packone(const float* __restrict__ W,
                                        _Float16* __restrict__ P,
                                        int K, int N, int off) {
    const int KS = K >> 5;
    int j = off & 7, lane = (off >> 3) & 63, rest = off >> 9;
    int ks = rest % KS, ct = rest / KS;
    int k = ks * 32 + ((lane >> 4) << 3) + j;
    int c = ct * 16 + (lane & 15);
    P[off] = (_Float16)W[k * N + c];
}

// ---- ALL weight packing in one launch (flat index ranges) ----
__global__ __launch_bounds__(256) void k_packall(
    const float* __restrict__ Wp0, const float* __restrict__ Wp1,
    const float* __restrict__ Wn0, const float* __restrict__ Wn1,
    const float* __restrict__ Wo0, const float* __restrict__ Wo1,
    const float* __restrict__ ngW1, const float* __restrict__ ngW2,
    const float* __restrict__ l0W1, const float* __restrict__ fcnW1,
    const float* __restrict__ fcnW2, const float* __restrict__ l0W2,
    _Float16* __restrict__ pWp0, _Float16* __restrict__ pWp1,
    _Float16* __restrict__ pWn0, _Float16* __restrict__ pWn1,
    _Float16* __restrict__ pWo0, _Float16* __restrict__ pWo1,
    _Float16* __restrict__ png1, _Float16* __restrict__ png2,
    _Float16* __restrict__ pWc, _Float16* __restrict__ pWa,
    _Float16* __restrict__ Wf_t, _Float16* __restrict__ Wl_t) {
    int idx = blockIdx.x * 256 + threadIdx.x;
    if (idx < 98304) {
        int seg = idx >> 14, off = idx & 16383;
        if (seg == 0) packone(Wp0, pWp0, 128, 128, off);
        else if (seg == 1) packone(Wp1, pWp1, 128, 128, off);
        else if (seg == 2) packone(Wn0, pWn0, 128, 128, off);
        else if (seg == 3) packone(Wn1, pWn1, 128, 128, off);
        else if (seg == 4) packone(Wo0, pWo0, 128, 128, off);
        else packone(Wo1, pWo1, 128, 128, off);
    } else if (idx < 229376) {
        int r = idx - 98304;
        if (r < 65536) packone(ngW1, png1, 256, 256, r);
        else packone(ngW2, png2, 256, 256, r - 65536);
    } else if (idx < 233472) {
        packone(l0W1 + 256 * 32, pWc, 128, 32, idx - 229376);
    } else if (idx < 234496) {
        packone(fcnW1, pWa, 32, 32, idx - 233472);
    } else {
        int off = idx - 234496;   // [0, 16384)
        int k = off & 31, c = off >> 5;
        Wf_t[c * 32 + k] = (_Float16)fcnW2[k * 512 + c];
        Wl_t[c * 32 + k] = (_Float16)l0W2[k * 512 + c];
    }
}

// ---- MFMA irrep_linear: 16 nodes/block, 4 waves. In-place safe.
__global__ __launch_bounds__(256) void k_irrep_m(
    const float* __restrict__ X, const _Float16* __restrict__ pW0,
    const float* __restrict__ b0, const _Float16* __restrict__ pW1,
    float* __restrict__ out) {
    __shared__ _Float16 Xr[4][16][136];
    const int t = threadIdx.x, lane = t & 63, w = t >> 6;
    const int nb = blockIdx.x * 16;
    for (int idx = t; idx < 16 * 128; idx += 256) {
        int n = idx >> 7, c4 = idx & 127;
        const float4 v = *(const float4*)(X + (size_t)(nb + n) * 512 + 4 * c4);
        float vals[4] = {v.x, v.y, v.z, v.w};
        int c = 4 * c4;
#pragma unroll
        for (int j = 0; j < 4; ++j) {
            int cc = c + j;
            if (cc < 128) Xr[0][n][cc] = (_Float16)vals[j];
            else { int d = cc - 128; Xr[1 + d % 3][n][d / 3] = (_Float16)vals[j]; }
        }
    }
    __syncthreads();
    const _Float16* pW = (w == 0) ? pW0 : pW1;
    const int row16 = lane & 15, kg = lane >> 4;
    f32x4 acc[8];
    const f32x4 zero = {0.0f, 0.0f, 0.0f, 0.0f};
#pragma unroll
    for (int ct = 0; ct < 8; ++ct) acc[ct] = zero;
    for (int ks = 0; ks < 4; ++ks) {
        const half8 a = *(const half8*)&Xr[w][row16][ks * 32 + kg * 8];
#pragma unroll
        for (int ct = 0; ct < 8; ++ct) {
            const half8 b = *(const half8*)(pW + (((ct * 4 + ks) * 64 + lane) << 3));
            acc[ct] = __builtin_amdgcn_mfma_f32_16x16x32_f16(a, b, acc[ct], 0, 0, 0);
        }
    }
#pragma unroll
    for (int ct = 0; ct < 8; ++ct) {
        const int col = ct * 16 + row16;
        const float bb = (w == 0) ? b0[col] : 0.0f;
#pragma unroll
        for (int r = 0; r < 4; ++r) {
            const int node = nb + kg * 4 + r;
            const float val = acc[ct][r] * RS128 + bb;
            if (w == 0) out[(size_t)node * 512 + col] = val;
            else out[(size_t)node * 512 + 128 + 3 * col + (w - 1)] = val;
        }
    }
}

// ---- MFMA fused norm_gate + irrep_linear(Wn) ----
__global__ __launch_bounds__(256) void k_self_m(
    const float* __restrict__ X,
    const _Float16* __restrict__ png1, const float* __restrict__ ngb1,
    const _Float16* __restrict__ png2, const float* __restrict__ ngb2,
    const _Float16* __restrict__ pWn0, const float* __restrict__ bn0,
    const _Float16* __restrict__ pWn1,
    float* __restrict__ selfx) {
    __shared__ _Float16 f0h[16][264];
    __shared__ _Float16 t1h[16][264];
    __shared__ _Float16 xvh[3][16][136];
    const int t = threadIdx.x, lane = t & 63, w = t >> 6;
    const int nb = blockIdx.x * 16;
    const int row16 = lane & 15, kg = lane >> 4;
    const f32x4 zero = {0.0f, 0.0f, 0.0f, 0.0f};

    for (int idx = t; idx < 16 * 128; idx += 256) {
        int n = idx >> 7, c4 = idx & 127;
        const float4 v = *(const float4*)(X + (size_t)(nb + n) * 512 + 4 * c4);
        float vals[4] = {v.x, v.y, v.z, v.w};
        int c = 4 * c4;
#pragma unroll
        for (int j = 0; j < 4; ++j) {
            int cc = c + j;
            if (cc < 128) f0h[n][cc] = (_Float16)vals[j];
            else { int d = cc - 128; xvh[d % 3][n][d / 3] = (_Float16)vals[j]; }
        }
    }
    __syncthreads();
    for (int idx = t; idx < 16 * 128; idx += 256) {
        int n = idx >> 7, u = idx & 127;
        float a = (float)xvh[0][n][u], b = (float)xvh[1][n][u], c = (float)xvh[2][n][u];
        f0h[n][128 + u] = (_Float16)sqrtf(fmaf(a, a, fmaf(b, b, fmaf(c, c, 1e-12f))));
    }
    __syncthreads();
    {
        f32x4 acc[4];
#pragma unroll
        for (int i = 0; i < 4; ++i) acc[i] = zero;
        for (int ks = 0; ks < 8; ++ks) {
            const half8 a = *(const half8*)&f0h[row16][ks * 32 + kg * 8];
#pragma unroll
            for (int c2 = 0; c2 < 4; ++c2) {
                const int ct = 4 * w + c2;
                const half8 b = *(const half8*)(png1 + (((ct * 8 + ks) * 64 + lane) << 3));
                acc[c2] = __builtin_amdgcn_mfma_f32_16x16x32_f16(a, b, acc[c2], 0, 0, 0);
            }
        }
#pragma unroll
        for (int c2 = 0; c2 < 4; ++c2) {
            const int col = (4 * w + c2) * 16 + row16;
            const float bb = ngb1[col];
#pragma unroll
            for (int r = 0; r < 4; ++r) {
                const float z = acc[c2][r] + bb;
                t1h[kg * 4 + r][col] = (_Float16)(z / (1.0f + __expf(-z)));
            }
        }
    }
    __syncthreads();
    {
        f32x4 acc[4];
#pragma unroll
        for (int i = 0; i < 4; ++i) acc[i] = zero;
        for (int ks = 0; ks < 8; ++ks) {
            const half8 a = *(const half8*)&t1h[row16][ks * 32 + kg * 8];
#pragma unroll
            for (int c2 = 0; c2 < 4; ++c2) {
                const int ct = 4 * w + c2;
                const half8 b = *(const half8*)(png2 + (((ct * 8 + ks) * 64 + lane) << 3));
                acc[c2] = __builtin_amdgcn_mfma_f32_16x16x32_f16(a, b, acc[c2], 0, 0, 0);
            }
        }
        __syncthreads();
#pragma unroll
        for (int c2 = 0; c2 < 4; ++c2) {
            const int col = (4 * w + c2) * 16 + row16;
            const float bb = ngb2[col];
#pragma unroll
            for (int r = 0; r < 4; ++r)
                f0h[kg * 4 + r][col] = (_Float16)(acc[c2][r] + bb);
        }
    }
    __syncthreads();
    for (int idx = t; idx < 16 * 128; idx += 256) {
        int n = idx >> 7, u = idx & 127;
        const _Float16 g = f0h[n][128 + u];
        xvh[0][n][u] = xvh[0][n][u] * g;
        xvh[1][n][u] = xvh[1][n][u] * g;
        xvh[2][n][u] = xvh[2][n][u] * g;
    }
    __syncthreads();
    {
        const _Float16* pw = (w == 0) ? pWn0 : pWn1;
        f32x4 acc[8];
#pragma unroll
        for (int ct = 0; ct < 8; ++ct) acc[ct] = zero;
        for (int ks = 0; ks < 4; ++ks) {
            const half8 a = (w == 0)
                ? *(const half8*)&f0h[row16][ks * 32 + kg * 8]
                : *(const half8*)&xvh[w - 1][row16][ks * 32 + kg * 8];
#pragma unroll
            for (int ct = 0; ct < 8; ++ct) {
                const half8 b = *(const half8*)(pw + (((ct * 4 + ks) * 64 + lane) << 3));
                acc[ct] = __builtin_amdgcn_mfma_f32_16x16x32_f16(a, b, acc[ct], 0, 0, 0);
            }
        }
#pragma unroll
        for (int ct = 0; ct < 8; ++ct) {
            const int col = ct * 16 + row16;
            const float bb = (w == 0) ? bn0[col] : 0.0f;
#pragma unroll
            for (int r = 0; r < 4; ++r) {
                const int node = nb + kg * 4 + r;
                const float val = acc[ct][r] * RS128 + bb;
                if (w == 0) selfx[(size_t)node * 512 + col] = val;
                else selfx[(size_t)node * 512 + 128 + 3 * col + (w - 1)] = val;
            }
        }
    }
}

// per-node halves of MLP1
__global__ __launch_bounds__(256) void k_pre(
    const float* __restrict__ prex, const float* __restrict__ l0W1,
    float* __restrict__ pAB) {
    __shared__ float xs[8][128];
    const int t = threadIdx.x;
    const int nb = blockIdx.x * 8;
    for (int idx = t; idx < 8 * 128; idx += 256) {
        int n = idx >> 7, u = idx & 127;
        xs[n][u] = prex[(size_t)(nb + n) * 512 + u];
    }
    __syncthreads();
    const int n = t >> 5, k = t & 31;
    float a = 0, b = 0;
    for (int u = 0; u < 128; ++u) {
        float s = xs[n][u];
        a = fmaf(s, l0W1[u * 32 + k], a);
        b = fmaf(s, l0W1[(128 + u) * 32 + k], b);
    }
    pAB[(size_t)(nb + n) * 64 + k] = a;
    pAB[(size_t)(nb + n) * 64 + 32 + k] = b;
}

// ---- CSR build ----
__global__ __launch_bounds__(256) void k_deg(const int* __restrict__ ei, int* __restrict__ deg) {
    int e = blockIdx.x * 256 + threadIdx.x;
    if (e < EE) atomicAdd(&deg[ei[e]], 1);
}

__global__ __launch_bounds__(1024) void k_scan(const int* __restrict__ deg, int* __restrict__ row_ptr) {
    __shared__ int part[1024];
    const int t = threadIdx.x;
    const int base = t * 10;
    int loc[10];
    int s = 0;
#pragma unroll
    for (int i = 0; i < 10; ++i) {
        int idx = base + i;
        int d = (idx < NN) ? deg[idx] : 0;
        loc[i] = s;
        s += d;
    }
    part[t] = s;
    __syncthreads();
    for (int off = 1; off < 1024; off <<= 1) {
        int v = (t >= off) ? part[t - off] : 0;
        __syncthreads();
        part[t] += v;
        __syncthreads();
    }
    int excl = (t > 0) ? part[t - 1] : 0;
#pragma unroll
    for (int i = 0; i < 10; ++i) {
        int idx = base + i;
        if (idx <= NN) row_ptr[idx] = excl + loc[i];
    }
}

__global__ __launch_bounds__(256) void k_fill(const int* __restrict__ ei,
                                              const int* __restrict__ row_ptr,
                                              int* __restrict__ cursor,
                                              int* __restrict__ csr_eid) {
    int e = blockIdx.x * 256 + threadIdx.x;
    if (e < EE) {
        int d = ei[e];
        int pos = atomicAdd(&cursor[d], 1);
        csr_eid[row_ptr[d] + pos] = e;
    }
}

// ---- MFMA hidden units, CSR-position order ----
__global__ __launch_bounds__(256) void k_hidden_m(
    const float* __restrict__ prex, const float* __restrict__ pAB,
    const int* __restrict__ edge_index, const float* __restrict__ edge_attr,
    const int* __restrict__ csr_eid,
    const _Float16* __restrict__ pWc, const _Float16* __restrict__ pWa,
    __half* __restrict__ hh) {
    const int pb = blockIdx.x * 32;
    const int t = threadIdx.x, lane = t & 63, w = t >> 6;
    __shared__ _Float16 ipl[32][132];
    __shared__ _Float16 eal[32][36];
    __shared__ _Float16 h1o[32][32];
    __shared__ _Float16 hao[32][32];
    __shared__ int dsts[32], srcs[32], eids[32];

    if (t < 32) {
        const int id = csr_eid[pb + t];
        eids[t] = id;
        dsts[t] = edge_index[id];
        srcs[t] = edge_index[EE + id];
    }
    __syncthreads();
    for (int idx = t; idx < 32 * 32; idx += 256) {
        int e = idx >> 5, j = idx & 31;
        eal[e][j] = (_Float16)edge_attr[(size_t)eids[e] * 32 + j];
    }
    for (int idx = t; idx < 32 * 128; idx += 256) {
        int e = idx >> 7, u = idx & 127;
        const float* pd = prex + (size_t)dsts[e] * 512 + 128 + 3 * u;
        const float* ps = prex + (size_t)srcs[e] * 512 + 128 + 3 * u;
        ipl[e][u] = (_Float16)((pd[0] * ps[0] + pd[1] * ps[1] + pd[2] * ps[2]) * R3);
    }
    __syncthreads();

    const int row16 = lane & 15, kg = lane >> 4;
    const int mt = w >> 1, ct = w & 1;
    const int e0 = mt * 16;
    const f32x4 zero = {0.0f, 0.0f, 0.0f, 0.0f};
    const int kc = ct * 16 + row16;

    {
        f32x4 acc = zero;
#pragma unroll
        for (int ks = 0; ks < 4; ++ks) {
            const half8 a = *(const half8*)&ipl[e0 + row16][ks * 32 + kg * 8];
            const half8 b = *(const half8*)(pWc + (((ct * 4 + ks) * 64 + lane) << 3));
            acc = __builtin_amdgcn_mfma_f32_16x16x32_f16(a, b, acc, 0, 0, 0);
        }
#pragma unroll
        for (int r = 0; r < 4; ++r) {
            const int e = e0 + kg * 4 + r;
            const float v = acc[r] + pAB[(size_t)dsts[e] * 64 + kc]
                                   + pAB[(size_t)srcs[e] * 64 + 32 + kc];
            h1o[e][kc] = (_Float16)sspf(v * RS384);
        }
    }
    {
        const half8 a = *(const half8*)&eal[e0 + row16][kg * 8];
        const half8 b = *(const half8*)(pWa + ((ct * 64 + lane) << 3));
        f32x4 acc = __builtin_amdgcn_mfma_f32_16x16x32_f16(a, b, zero, 0, 0, 0);
#pragma unroll
        for (int r = 0; r < 4; ++r) {
            const int e = e0 + kg * 4 + r;
            hao[e][kc] = (_Float16)sspf((float)acc[r] * RS32);
        }
    }
    __syncthreads();
    for (int idx = t; idx < 32 * 32; idx += 256) {
        const int e = idx >> 5, j = idx & 31;
        unsigned vv;
        if (j < 16) {
            __half2 h2 = __halves2half2((__half)h1o[e][2 * j], (__half)h1o[e][2 * j + 1]);
            vv = *(unsigned*)&h2;
        } else {
            const int jj = j - 16;
            __half2 h2 = __halves2half2((__half)hao[e][2 * jj], (__half)hao[e][2 * jj + 1]);
            vv = *(unsigned*)&h2;
        }
        ((unsigned*)hh)[(size_t)(pb + e) * 32 + j] = vv;
    }
}

// ---- per-dst accumulate via MFMA; flat chunk list over 8 dsts, double-buffered pipeline ----
__global__ __launch_bounds__(512) void k_accum(
    const __half* __restrict__ hh, const float* __restrict__ selfx,
    const int* __restrict__ edge_index, const float* __restrict__ edge_sh,
    const int* __restrict__ row_ptr, const int* __restrict__ csr_eid,
    const _Float16* __restrict__ Wf_t, const _Float16* __restrict__ Wl_t,
    float* __restrict__ outacc) {
    const int dst0 = blockIdx.x * DPB;
    const int t = threadIdx.x;
    const int lane = t & 63;
    const int wid = t >> 6;
    const int lcol = lane & 15;
    const int kg = lane >> 4;
    const int u = 16 * wid + lcol;
    const int koff = kg * 8;

    __shared__ __align__(16) _Float16 h1s[2][4][16][8];
    __shared__ __align__(16) _Float16 has[2][4][16][8];
    __shared__ float shl[2][16][4];
    __shared__ int srcs[2][16];
    __shared__ int cbeg[DPB], cne[DPB], cchk[DPB + 1];

    if (t < DPB) {
        const int b = row_ptr[dst0 + t];
        cbeg[t] = b;
        cne[t] = row_ptr[dst0 + t + 1] - b;
    }
    __syncthreads();
    if (t == 0) {
        int s = 0;
#pragma unroll
        for (int i = 0; i < DPB; ++i) { cchk[i] = s; s += max(1, (cne[i] + 15) >> 4); }
        cchk[DPB] = s;
    }
    // weight fragments (independent of LDS) — load while prefix computes
    half8 bf[4], bl[4];
#pragma unroll
    for (int q = 0; q < 4; ++q) {
        const int col = q * 128 + u;
        bf[q] = *(const half8*)(Wf_t + col * 32 + koff);
        bl[q] = *(const half8*)(Wl_t + col * 32 + koff);
    }
    __syncthreads();
    const int nc = cchk[DPB];
    const float inv32 = 1.0f / 32.0f;

    float acc0 = 0, acc1 = 0, acc2 = 0, acc3 = 0;

    // staging registers
    unsigned rhh = 0;
    int rsrc = 0;
    float4 rsh = {0.0f, 0.0f, 0.0f, 0.0f};

    const int se = t >> 5, sw = t & 31;   // staging roles

    auto issue = [&](int ci) {
        int dd = 0;
        while (dd + 1 < DPB && ci >= cchk[dd + 1]) ++dd;
        const int c0 = (ci - cchk[dd]) << 4;
        const int ce = min(16, cne[dd] - c0);
        const int pos = cbeg[dd] + c0;
        rhh = (se < ce) ? ((const unsigned*)hh)[(size_t)(pos + se) * 32 + sw] : 0u;
        if (t < 16) {
            if (t < ce) {
                const int id = csr_eid[pos + t];
                rsrc = edge_index[EE + id];
                rsh = *(const float4*)(edge_sh + (size_t)id * 4);
            } else {
                rsrc = 0;
                rsh = make_float4(0.0f, 0.0f, 0.0f, 0.0f);
            }
        }
    };

    auto flush = [&](int dd) {
        acc0 += __shfl_xor(acc0, 16, 64); acc0 += __shfl_xor(acc0, 32, 64);
        acc1 += __shfl_xor(acc1, 16, 64); acc1 += __shfl_xor(acc1, 32, 64);
        acc2 += __shfl_xor(acc2, 16, 64); acc2 += __shfl_xor(acc2, 32, 64);
        acc3 += __shfl_xor(acc3, 16, 64); acc3 += __shfl_xor(acc3, 32, 64);
        if (lane < 16) {
            const size_t g = (size_t)(dst0 + dd) * 512;
            outacc[g + u] = acc0 + selfx[g + u];
            outacc[g + 128 + 3 * u + 0] = acc1 + selfx[g + 128 + 3 * u + 0];
            outacc[g + 128 + 3 * u + 1] = acc2 + selfx[g + 128 + 3 * u + 1];
            outacc[g + 128 + 3 * u + 2] = acc3 + selfx[g + 128 + 3 * u + 2];
        }
        acc0 = acc1 = acc2 = acc3 = 0;
    };

    issue(0);
    int cur = 0, cur_dd = 0;
    for (int ci = 0; ci < nc; ++ci) {
        // commit staged regs into LDS[cur]
        if (sw < 16) ((unsigned*)h1s[cur])[(sw >> 2) * 64 + se * 4 + (sw & 3)] = rhh;
        else         ((unsigned*)has[cur])[((sw - 16) >> 2) * 64 + se * 4 + ((sw - 16) & 3)] = rhh;
        if (t < 16) {
            srcs[cur][t] = rsrc;
            shl[cur][t][0] = rsh.x; shl[cur][t][1] = rsh.y;
            shl[cur][t][2] = rsh.z; shl[cur][t][3] = rsh.w;
        }
        // chunk meta for this iteration
        int dd = 0;
        while (dd + 1 < DPB && ci >= cchk[dd + 1]) ++dd;
        const int c0 = (ci - cchk[dd]) << 4;
        const int ce = min(16, cne[dd] - c0);
        // prefetch next chunk (loads overlap barrier + compute)
        if (ci + 1 < nc) issue(ci + 1);
        __syncthreads();
        if (dd != cur_dd) { flush(cur_dd); cur_dd = dd; }

        const half8 haf = *(const half8*)(&has[cur][kg][lcol][0]);
        const half8 h1f = *(const half8*)(&h1s[cur][kg][lcol][0]);
        const f32x4 zero = {0.0f, 0.0f, 0.0f, 0.0f};
        f32x4 A[4], B[4];
#pragma unroll
        for (int q = 0; q < 4; ++q) {
            A[q] = __builtin_amdgcn_mfma_f32_16x16x32_f16(haf, bf[q], zero, 0, 0, 0);
            B[q] = __builtin_amdgcn_mfma_f32_16x16x32_f16(h1f, bl[q], zero, 0, 0, 0);
        }
#pragma unroll
        for (int r = 0; r < 4; ++r) {
            const int e = kg * 4 + r;
            if (e < ce) {
                const float w1 = A[0][r] * B[0][r] * inv32;
                const float w2 = A[1][r] * B[1][r] * inv32;
                const float w3 = A[2][r] * B[2][r] * inv32;
                const float w4 = A[3][r] * B[3][r] * inv32;
                const int src = srcs[cur][e];
                const float sh0 = shl[cur][e][0], s1x = shl[cur][e][1];
                const float s1y = shl[cur][e][2], s1z = shl[cur][e][3];
                const float* sr = selfx + (size_t)src * 512;
                const float xs0 = sr[u];
                const float* sv = sr + 128 + 3 * u;
                const float xv0 = sv[0], xv1 = sv[1], xv2 = sv[2];
                const float dv = xv0 * s1x + xv1 * s1y + xv2 * s1z;
                acc0 += 0.5f * (w1 * xs0 * sh0 + w4 * dv * R3);
                acc1 += C1V * (w2 * xs0 * s1x + w3 * xv0 * sh0);
                acc2 += C1V * (w2 * xs0 * s1y + w3 * xv1 * sh0);
                acc3 += C1V * (w2 * xs0 * s1z + w3 * xv2 * sh0);
            }
        }
        cur ^= 1;
    }
    flush(cur_dd);
}

extern "C" void kernel_launch(void* const* d_in, const int* in_sizes, int n_in,
                              void* d_out, int out_size, void* d_ws, size_t ws_size,
                              hipStream_t stream) {
    const float* x = (const float*)d_in[0];
    const int* edge_index = (const int*)d_in[1];
    const float* edge_attr = (const float*)d_in[2];
    const float* edge_sh = (const float*)d_in[3];
    const float* Wp0 = (const float*)d_in[4];
    const float* bp0 = (const float*)d_in[5];
    const float* Wp1 = (const float*)d_in[6];
    const float* ngW1 = (const float*)d_in[7];
    const float* ngb1 = (const float*)d_in[8];
    const float* ngW2 = (const float*)d_in[9];
    const float* ngb2 = (const float*)d_in[10];
    const float* Wn0 = (const float*)d_in[11];
    const float* bn0 = (const float*)d_in[12];
    const float* Wn1 = (const float*)d_in[13];
    const float* fcnW1 = (const float*)d_in[14];
    const float* fcnW2 = (const float*)d_in[15];
    const float* l0W1 = (const float*)d_in[16];
    const float* l0W2 = (const float*)d_in[17];
    const float* Wo0 = (const float*)d_in[18];
    const float* bo0 = (const float*)d_in[19];
    const float* Wo1 = (const float*)d_in[20];

    float* out = (float*)d_out;
    float* prex = out;                       // d_out as pre_x scratch; k_accum overwrites it
    float* selfx = (float*)d_ws;
    int* deg = (int*)(selfx + (size_t)NN * 512);
    int* cursor = deg + NN;
    int* row_ptr = cursor + NN;
    int* csr_eid = row_ptr + NN + 1;
    float* pAB = (float*)(csr_eid + EE);
    __half* hh = (__half*)(pAB + (size_t)NN * 64);
    _Float16* Wf_t = (_Float16*)(hh + (size_t)EE * 64);
    _Float16* Wl_t = Wf_t + 512 * 32;
    _Float16* pWp0 = Wl_t + 512 * 32;
    _Float16* pWp1 = pWp0 + 128 * 128;
    _Float16* pWn0 = pWp1 + 128 * 128;
    _Float16* pWn1 = pWn0 + 128 * 128;
    _Float16* pWo0 = pWn1 + 128 * 128;
    _Float16* pWo1 = pWo0 + 128 * 128;
    _Float16* png1 = pWo1 + 128 * 128;
    _Float16* png2 = png1 + 256 * 256;
    _Float16* pWc  = png2 + 256 * 256;
    _Float16* pWa  = pWc + 128 * 32;

    hipMemsetAsync(deg, 0, 2 * NN * sizeof(int), stream);  // deg + cursor

    k_packall<<<980, 256, 0, stream>>>(Wp0, Wp1, Wn0, Wn1, Wo0, Wo1, ngW1, ngW2,
                                       l0W1, fcnW1, fcnW2, l0W2,
                                       pWp0, pWp1, pWn0, pWn1, pWo0, pWo1,
                                       png1, png2, pWc, pWa, Wf_t, Wl_t);

    k_irrep_m<<<NN / 16, 256, 0, stream>>>(x, pWp0, bp0, pWp1, prex);
    k_pre<<<NN / 8, 256, 0, stream>>>(prex, l0W1, pAB);
    k_self_m<<<NN / 16, 256, 0, stream>>>(x, ngW1 ? png1 : png1, ngb1, png2, ngb2, pWn0, bn0, pWn1, selfx);
    k_deg<<<EE / 256, 256, 0, stream>>>(edge_index, deg);
    k_scan<<<1, 1024, 0, stream>>>(deg, row_ptr);
    k_fill<<<EE / 256, 256, 0, stream>>>(edge_index, row_ptr, cursor, csr_eid);
    k_hidden_m<<<EE / 32, 256, 0, stream>>>(prex, pAB, edge_index, edge_attr, csr_eid,
                                            pWc, pWa, hh);
    k_accum<<<NN / DPB, 512, 0, stream>>>(hh, selfx, edge_index, edge_sh, row_ptr, csr_eid,
                                          Wf_t, Wl_t, out);
    k_irrep_m<<<NN / 16, 256, 0, stream>>>(out, pWo0, bo0, pWo1, out);
}